// Round 17
// baseline (469.090 us; speedup 1.0000x reference)
//
#include <hip/hip_runtime.h>
#include <cstddef>
#include <cstdint>

// ---------------- problem constants ----------------
// b=2, s=256, WIDTH=64, RANK=4, CLEVEL=1 (c=2), MLEVEL=2 (L=3), NB=4
// HID1=64, HID2=128

// ---------------- workspace layout (float-slot offsets) ----------------
// x1/yl1/yl2/x2c/H2psi/H2phi/h are bf16.
static constexpr size_t OFF_X1     = 0;          // bf16 2*256*256*64 -> 4194304 slots
static constexpr size_t OFF_YL1    = 4194304;    // bf16 -> 1048576
static constexpr size_t OFF_YL2    = 5242880;    // bf16 -> 262144
static constexpr size_t OFF_HBF    = 5505024;    // bf16 h -> 4194304
static constexpr size_t OFF_H2PSI  = 9699328;    // bf16 32768*128 -> 2097152 (x2c overlays)
static constexpr size_t OFF_H2PHI  = 11796480;   // 2097152
static constexpr size_t OFF_CWTBF  = 13893632;   // 221184
static constexpr size_t OFF_Q1BF   = 14114816;   // 4096
static constexpr size_t OFF_W2T    = 14118912;   // 8*8192 bf16 = 32768 float-slots
static constexpr size_t OFF_GPART  = 14151680;   // 512*8192 f32 = 4194304
static constexpr size_t OFF_SVP    = 18345984;   // 32768
static constexpr size_t OFF_G      = 18378752;   // 16384
static constexpr size_t OFF_SV     = 18395136;   // 128
// end = 18395264 floats (~73.6 MB) <= proven-available 134.3 MB

typedef __attribute__((ext_vector_type(8)))  short bf16x8_t;   // 8 bf16 in 4 VGPRs
typedef __attribute__((ext_vector_type(16))) float f32x16_t;   // 32x32 MFMA acc

// ---------------- helpers ----------------
__device__ inline float wave_sum64(float v) {
    v += __shfl_xor(v, 1);
    v += __shfl_xor(v, 2);
    v += __shfl_xor(v, 4);
    v += __shfl_xor(v, 8);
    v += __shfl_xor(v, 16);
    v += __shfl_xor(v, 32);
    return v;
}

__device__ inline unsigned short f2bf(float f) {   // round-to-nearest-even
    uint32_t u = __float_as_uint(f);
    uint32_t r = u + 0x7FFFu + ((u >> 16) & 1u);
    return (unsigned short)(r >> 16);
}
__device__ inline float bf2f(unsigned short u) {
    return __uint_as_float((uint32_t)u << 16);
}
// 8 bf16 (uint4) -> 8 f32
__device__ inline void bf8_to_f(uint4 u, float* d) {
    unsigned uv[4] = {u.x, u.y, u.z, u.w};
#pragma unroll
    for (int i = 0; i < 4; ++i) {
        d[2 * i]     = __uint_as_float((uv[i] & 0xFFFFu) << 16);
        d[2 * i + 1] = __uint_as_float(uv[i] & 0xFFFF0000u);
    }
}

// full-res flat pixel index of coarse pixel (b, n): n in [0,16384)
__device__ inline size_t fullpix(int b, int n) {
    return (size_t)(b * 65536 + (n >> 7) * 512 + ((n & 127) << 1));
}

struct Lerp { int i0, i1; float f; };
__device__ inline Lerp lcoord(int o, float r, float off, int Sin) {
    float s = fmaxf(fmaf((float)o, r, off), 0.f);
    Lerp L;
    L.i0 = (int)s;
    L.f  = s - (float)L.i0;
    L.i1 = min(L.i0 + 1, Sin - 1);
    return L;
}

// ---------------- fused setup: convW | q1 | W2 frag-order | lift ----------------
// grid 2528: [0,1728) convW; [1728,1760) q1; [1760,2016) W2t; [2016,2528) lift
__global__ __launch_bounds__(256) void k_setup(const float* __restrict__ convW,
                                               unsigned short* __restrict__ cwt,
                                               const float* __restrict__ q1W,
                                               unsigned short* __restrict__ q1bf,
                                               const float* __restrict__ psiW2,
                                               const float* __restrict__ phiW2,
                                               unsigned short* __restrict__ w2t,
                                               const float* __restrict__ x,
                                               const float* __restrict__ a,
                                               const float* __restrict__ pW,
                                               const float* __restrict__ pb,
                                               unsigned short* __restrict__ hbf) {
    int bid = blockIdx.x;
    int t = threadIdx.x;
    if (bid < 1728) {
        // convW[i][l][oc][ic][3][3] f32 -> wt[((il*9+tap)*4+kq)*1024 + hi*512 + oc*8 + j]
        int idx = bid * 256 + t;                  // 442368
        if (idx >= 442368) return;
        int j    = idx & 7;
        int oc   = (idx >> 3) & 63;
        int hi   = (idx >> 9) & 1;
        int kq   = (idx >> 10) & 3;
        int rest = idx >> 12;                     // il*9 + tap
        int tap  = rest % 9;
        int il   = rest / 9;
        int ic   = kq * 16 + hi * 8 + j;
        cwt[idx] = f2bf(convW[((size_t)(il * 64 + oc) * 64 + ic) * 9 + tap]);
    } else if (bid < 1760) {
        int idx = (bid - 1728) * 256 + t;         // 8192
        int k = idx & 63;
        int j = idx >> 6;
        q1bf[j * 64 + k] = f2bf(q1W[k * 128 + j]);
    } else if (bid < 2016) {
        // W2[m][i][64 k][128 j] -> w2t[((((m*4+i)*4+jt)*4+kq)*2+hi)*256 + lo*8 + jj]
        int idx = (bid - 1760) * 256 + t;         // 65536
        int jj = idx & 7;
        int lo = (idx >> 3) & 31;
        int hi = (idx >> 8) & 1;
        int kq = (idx >> 9) & 3;
        int jt = (idx >> 11) & 3;
        int i  = (idx >> 13) & 3;
        int m  = idx >> 15;
        int k  = kq * 16 + hi * 8 + jj;
        int j  = jt * 32 + lo;
        const float* W2 = m ? phiW2 : psiW2;
        w2t[idx] = f2bf(W2[(size_t)i * 8192 + k * 128 + j]);
    } else {
        int p = (bid - 2016) * 256 + t;           // 131072
        float a0 = a[(size_t)p * 2 + 0];
        float a1 = a[(size_t)p * 2 + 1];
        float xv = x[p];
        float vals[64];
#pragma unroll
        for (int c = 0; c < 64; ++c)
            vals[c] = fmaf(a0, pW[c], fmaf(a1, pW[64 + c], fmaf(xv, pW[128 + c], pb[c])));
        unsigned short us[64];
#pragma unroll
        for (int c = 0; c < 64; ++c) us[c] = f2bf(vals[c]);
        unsigned short* bp = hbf + (size_t)p * 64;
#pragma unroll
        for (int c = 0; c < 64; c += 8)
            *(uint4*)(bp + c) = *(uint4*)(us + c);
    }
}

// ---------------- fused conv (blocks 0..671) + mlp-MFMA (blocks 672..1695) ----------------
// conv: A-only LDS, frag-order B from L2 (reg dbuf), C-tile transposed through LDS
//       for coalesced uint4 stores.  mlp: h1 per-lane + W2-GEMM via MFMA.
__global__ __launch_bounds__(256) void k_convmlp(
    const unsigned short* __restrict__ hbf,   // [2][256][256][64] bf16
    const unsigned short* __restrict__ wbf,   // conv W frag-order, 36864 per (iter,lvl)
    const float* __restrict__ convb,          // [12][64]
    unsigned short* __restrict__ x1, unsigned short* __restrict__ yl1,
    unsigned short* __restrict__ yl2,
    const float* __restrict__ a, const float* __restrict__ x,
    const float* __restrict__ W1a, const float* __restrict__ b1a,
    const float* __restrict__ b2a,
    const float* __restrict__ W1b, const float* __restrict__ b1b,
    const float* __restrict__ b2b,
    const unsigned short* __restrict__ w2t,   // mlp W2 frag-order
    unsigned short* __restrict__ H2a, unsigned short* __restrict__ H2b,
    int iter) {
    __shared__ unsigned short Ald[20736];     // conv: A halo, then reused as C tile
    int bid = blockIdx.x;
    int t = threadIdx.x;

    if (bid >= 672) {
        // ---------------- mlp path (MFMA) ----------------
        int blk = bid - 672;                       // 0..1023
        int m = blk >> 9;                          // 0=psi, 1=phi
        int px0 = (blk & 511) << 6;                // 64 px per block
        const float* W1 = m ? W1b : W1a;
        const float* b1 = m ? b1b : b1a;
        const float* b2 = m ? b2b : b2a;
        unsigned short* H2 = m ? H2b : H2a;

        int w    = t >> 6;                         // j-tile 0..3
        int lane = t & 63;
        int lo   = lane & 31;
        int hi   = lane >> 5;

        int pxlA = px0 + lo, pxlB = px0 + 32 + lo;
        int bA = pxlA >> 14;
        size_t apA = fullpix(bA, pxlA & 16383);
        size_t apB = fullpix(bA, pxlB & 16383);
        float a0A = a[apA * 2], a1A = a[apA * 2 + 1], xvA = x[apA];
        float a0B = a[apB * 2], a1B = a[apB * 2 + 1], xvB = x[apB];

        bf16x8_t faA[4], faB[4];
#pragma unroll
        for (int kq = 0; kq < 4; ++kq) {
            unsigned short tA[8], tB[8];
#pragma unroll
            for (int jj = 0; jj < 8; ++jj) {
                int k = kq * 16 + hi * 8 + jj;
                float w1a = W1[k], w1b = W1[64 + k], w1c = W1[128 + k], bb = b1[k];
                tA[jj] = f2bf(fmaxf(fmaf(a0A, w1a, fmaf(a1A, w1b, fmaf(xvA, w1c, bb))), 0.f));
                tB[jj] = f2bf(fmaxf(fmaf(a0B, w1a, fmaf(a1B, w1b, fmaf(xvB, w1c, bb))), 0.f));
            }
            faA[kq] = *(bf16x8_t*)tA;
            faB[kq] = *(bf16x8_t*)tB;
        }
        const unsigned short* wb =
            w2t + (size_t)(((m * 4 + iter) * 4 + w) * 4) * 512 + hi * 256 + lo * 8;
        f32x16_t accA = {}, accB = {};
#pragma unroll
        for (int kq = 0; kq < 4; ++kq) {
            bf16x8_t fb = *(const bf16x8_t*)(wb + kq * 512);
            accA = __builtin_amdgcn_mfma_f32_32x32x16_bf16(faA[kq], fb, accA, 0, 0, 0);
            accB = __builtin_amdgcn_mfma_f32_32x32x16_bf16(faB[kq], fb, accB, 0, 0, 0);
        }
        float bias2 = b2[w * 32 + lo];
#pragma unroll
        for (int reg = 0; reg < 16; ++reg) {
            int row = (reg & 3) + 8 * (reg >> 2) + 4 * hi;
            H2[(size_t)(px0 + row) * 128 + w * 32 + lo]      = f2bf(fmaxf(accA[reg] + bias2, 0.f));
            H2[(size_t)(px0 + 32 + row) * 128 + w * 32 + lo] = f2bf(fmaxf(accB[reg] + bias2, 0.f));
        }
        return;
    }

    // ---------------- conv path ----------------
    int lvl, tix, Sl, st, tpr;
    if (bid < 512)      { lvl = 0; tix = bid;       Sl = 256; st = 1; tpr = 16; }
    else if (bid < 640) { lvl = 1; tix = bid - 512; Sl = 128; st = 2; tpr = 8;  }
    else                { lvl = 2; tix = bid - 640; Sl = 64;  st = 4; tpr = 4;  }
    int tpb = tpr * tpr;
    int b = tix / tpb;
    int r = tix - b * tpb;
    int y0 = (r / tpr) * 16, x0 = (r % tpr) * 16;

    // ---- stage A: 18x18 halo x 64 ic, zero-padded ----
    for (int c = t; c < 2592; c += 256) {
        int lin = c >> 3, slot = c & 7;
        int ty = lin / 18, tx = lin - ty * 18;
        int oy = y0 + ty - 1, ox = x0 + tx - 1;
        uint4 val = make_uint4(0u, 0u, 0u, 0u);
        if ((unsigned)oy < (unsigned)Sl && (unsigned)ox < (unsigned)Sl) {
            const unsigned short* src =
                hbf + (((size_t)(b * 256 + oy * st) * 256 + ox * st) << 6) + (slot << 3);
            val = *(const uint4*)src;
        }
        int byte = (lin << 7) + (((slot ^ (lin & 7))) << 4);
        *(uint4*)((char*)Ald + byte) = val;
    }
    __syncthreads();

    int w    = t >> 6;
    int lane = t & 63;
    int lo   = lane & 31;
    int hi   = lane >> 5;
    f32x16_t acc00 = {}, acc01 = {}, acc10 = {}, acc11 = {};

    const unsigned short* wbase =
        wbf + (size_t)(iter * 3 + lvl) * 36864 + hi * 512 + lo * 8;

    int yA0 = 4 * w + (lo >> 4);
    int xA  = lo & 15;

    bf16x8_t v0c[4], v1c[4], v0n[4], v1n[4];
#pragma unroll
    for (int kq = 0; kq < 4; ++kq) {
        v0c[kq] = *(const bf16x8_t*)(wbase + kq * 1024);
        v1c[kq] = *(const bf16x8_t*)(wbase + kq * 1024 + 256);
    }
#pragma unroll
    for (int tap = 0; tap < 9; ++tap) {
        if (tap < 8) {
#pragma unroll
            for (int kq = 0; kq < 4; ++kq) {
                int keo = ((tap + 1) * 4 + kq) * 1024;
                v0n[kq] = *(const bf16x8_t*)(wbase + keo);
                v1n[kq] = *(const bf16x8_t*)(wbase + keo + 256);
            }
        }
        int dy = tap / 3, dx = tap - dy * 3;
        int lin0 = (yA0 + dy) * 18 + (xA + dx);
        int lin1 = lin0 + 36;
#pragma unroll
        for (int kq = 0; kq < 4; ++kq) {
            int icb = (kq << 5) + (hi << 4);            // byte offset in A row
            int a0b = ((lin0 << 7) + icb) ^ ((lin0 & 7) << 4);
            int a1b = ((lin1 << 7) + icb) ^ ((lin1 & 7) << 4);
            bf16x8_t va0 = *(bf16x8_t*)((char*)Ald + a0b);
            bf16x8_t va1 = *(bf16x8_t*)((char*)Ald + a1b);
            acc00 = __builtin_amdgcn_mfma_f32_32x32x16_bf16(va0, v0c[kq], acc00, 0, 0, 0);
            acc01 = __builtin_amdgcn_mfma_f32_32x32x16_bf16(va0, v1c[kq], acc01, 0, 0, 0);
            acc10 = __builtin_amdgcn_mfma_f32_32x32x16_bf16(va1, v0c[kq], acc10, 0, 0, 0);
            acc11 = __builtin_amdgcn_mfma_f32_32x32x16_bf16(va1, v1c[kq], acc11, 0, 0, 0);
        }
#pragma unroll
        for (int kq = 0; kq < 4; ++kq) { v0c[kq] = v0n[kq]; v1c[kq] = v1n[kq]; }
    }

    // ---- transpose C through LDS (Ald dead), then coalesced uint4 stores ----
    __syncthreads();                 // all waves done reading Ald
    unsigned short* Cld = Ald;       // [16 y][16 x][64 oc] bf16 = 32 KB
    const float* bias = convb + (iter * 3 + lvl) * 64;
    float bias0 = bias[lo];
    float bias1 = bias[32 + lo];
#pragma unroll
    for (int reg = 0; reg < 16; ++reg) {
        int row = (reg & 3) + 8 * (reg >> 2) + 4 * hi;
        int yt  = 4 * w + (row >> 4);
        int xt  = row & 15;
        int px0l = (yt * 16 + xt) << 6;
        Cld[px0l + lo]      = f2bf(acc00[reg] + bias0);
        Cld[px0l + 32 + lo] = f2bf(acc01[reg] + bias1);
        int px1l = ((yt + 2) * 16 + xt) << 6;
        Cld[px1l + lo]      = f2bf(acc10[reg] + bias0);
        Cld[px1l + 32 + lo] = f2bf(acc11[reg] + bias1);
    }
    __syncthreads();
    unsigned short* out = (lvl == 0) ? x1 : (lvl == 1 ? yl1 : yl2);
#pragma unroll
    for (int rr = 0; rr < 8; ++rr) {
        int f  = rr * 256 + t;       // uint4 index 0..2047
        int yt = f >> 7;             // 128 uint4 per output row
        int c  = f & 127;
        unsigned short* dst = out + (((size_t)(b * Sl + y0 + yt) * Sl + x0) << 6) + c * 8;
        *(uint4*)dst = ((const uint4*)Cld)[f];
    }
}

// ---------------- split-K stage 1: Gpart[blk] = v^T H2psi over 64 px; svpart ----------------
__global__ __launch_bounds__(256) void k_gpart(const unsigned short* __restrict__ hbf,
                                               const unsigned short* __restrict__ H2psi,
                                               float* __restrict__ Gpart,
                                               float* __restrict__ svpart) {
    __shared__ float vt[4096];       // [64 px][64 w]
    __shared__ float h2t[8192];      // [64 px][128 j]
    int blk = blockIdx.x;            // 512
    int b = blk >> 8;
    int n0 = (blk & 255) << 6;
    int t = threadIdx.x;
    int pxq = t >> 2, qq = t & 3;
    int sw = (pxq & 7) << 4;
    {
        const unsigned short* src = hbf + fullpix(b, n0 + pxq) * 64 + qq * 16;
        uint4 u0 = *(const uint4*)src;
        uint4 u1 = *(const uint4*)(src + 8);
        float f[16];
        bf8_to_f(u0, f);
        bf8_to_f(u1, f + 8);
#pragma unroll
        for (int j = 0; j < 4; ++j) {
            int byte = (pxq * 256 + qq * 64 + j * 16) ^ sw;
            *(float4*)((char*)vt + byte) = make_float4(f[4 * j], f[4 * j + 1],
                                                       f[4 * j + 2], f[4 * j + 3]);
        }
        const unsigned short* hsrc = H2psi + ((size_t)(b * 16384 + n0 + pxq)) * 128 + qq * 32;
#pragma unroll
        for (int rr = 0; rr < 4; ++rr) {
            uint4 hu = *(const uint4*)(hsrc + rr * 8);
            float g[8];
            bf8_to_f(hu, g);
            int byte0 = (pxq * 512 + qq * 128 + rr * 32) ^ sw;
            int byte1 = (pxq * 512 + qq * 128 + rr * 32 + 16) ^ sw;
            *(float4*)((char*)h2t + byte0) = make_float4(g[0], g[1], g[2], g[3]);
            *(float4*)((char*)h2t + byte1) = make_float4(g[4], g[5], g[6], g[7]);
        }
    }
    __syncthreads();

    int wt_ = (t >> 5) << 3;         // 0..56
    int kt  = (t & 31) << 2;         // 0..124
    float acc[8][4];
#pragma unroll
    for (int i = 0; i < 8; ++i)
#pragma unroll
        for (int j = 0; j < 4; ++j) acc[i][j] = 0.f;

#pragma unroll 4
    for (int nn = 0; nn < 64; ++nn) {
        int nsw = (nn & 7) << 4;
        float4 hv = *(float4*)((char*)h2t + ((nn * 512 + kt * 4) ^ nsw));
        float4 v0 = *(float4*)((char*)vt + ((nn * 256 + wt_ * 4) ^ nsw));
        float4 v1 = *(float4*)((char*)vt + ((nn * 256 + wt_ * 4 + 16) ^ nsw));
        float vv[8] = {v0.x, v0.y, v0.z, v0.w, v1.x, v1.y, v1.z, v1.w};
        float hh[4] = {hv.x, hv.y, hv.z, hv.w};
#pragma unroll
        for (int i = 0; i < 8; ++i)
#pragma unroll
            for (int j = 0; j < 4; ++j) acc[i][j] = fmaf(vv[i], hh[j], acc[i][j]);
    }

    float* gp = Gpart + (size_t)blk * 8192;
#pragma unroll
    for (int i = 0; i < 8; ++i)
        *(float4*)&gp[(wt_ + i) * 128 + kt] =
            make_float4(acc[i][0], acc[i][1], acc[i][2], acc[i][3]);

    if (t < 64) {
        float s = 0.f;
#pragma unroll 8
        for (int p = 0; p < 64; ++p)
            s += *(float*)((char*)vt + ((p * 256 + t * 4) ^ ((p & 7) << 4)));
        svpart[blk * 64 + t] = s;
    }
}

// ---------------- reduce: G = sum Gpart; sv = sum svpart (grid 258) ----------------
__global__ __launch_bounds__(256) void k_gred(const float* __restrict__ Gpart,
                                              const float* __restrict__ svpart,
                                              float* __restrict__ G,
                                              float* __restrict__ sv) {
    __shared__ float red[4][64];
    int blk = blockIdx.x;
    int t = threadIdx.x;
    if (blk < 256) {
        int b  = blk >> 7;
        int es = (blk & 127) << 6;
        int e  = es + (t & 63);
        int cg = t >> 6;
        float s = 0.f;
        const float* gp = Gpart + ((size_t)(b * 256 + cg * 64)) * 8192 + e;
#pragma unroll 8
        for (int c = 0; c < 64; ++c) s += gp[(size_t)c * 8192];
        red[cg][t & 63] = s;
        __syncthreads();
        if (t < 64)
            G[b * 8192 + es + t] = red[0][t] + red[1][t] + red[2][t] + red[3][t];
    } else {
        int b = blk - 256;
        int w = t & 63, cg = t >> 6;
        float s = 0.f;
        const float* sp = svpart + ((size_t)(b * 256 + cg * 64)) * 64 + w;
#pragma unroll 8
        for (int c = 0; c < 64; ++c) s += sp[c * 64];
        red[cg][w] = s;
        __syncthreads();
        if (t < 64) sv[b * 64 + t] = red[0][t] + red[1][t] + red[2][t] + red[3][t];
    }
}

// ---------------- fused yc + x2c (grid 1024): ybar/C/D in-block, then x2c GEMM ----------------
__global__ __launch_bounds__(256) void k_x2cyc(const float* __restrict__ G,
                                               const float* __restrict__ sv,
                                               const float* __restrict__ W3psi,
                                               const float* __restrict__ b3psi,
                                               const float* __restrict__ W3phi,
                                               const float* __restrict__ b3phi,
                                               const unsigned short* __restrict__ H2phi,
                                               unsigned short* __restrict__ x2c) {
    __shared__ float ybar[256];
    __shared__ float cl[8192];       // C[b]: [64 w][128 k] (32 KB)
    __shared__ float h2l[4096];      // [32 px][128 k], XOR-swizzled (16 KB)
    __shared__ float Dl[64];
    int blk = blockIdx.x;            // 1024: 512 per b
    int b = blk >> 9;
    int px0 = (blk & 511) << 5;      // 32 px per block
    int t = threadIdx.x;

    {   // stage H2phi tile (bf16 -> f32), swizzled — independent of ybar
        const unsigned short* hsrc = H2phi + ((size_t)(b * 16384 + px0)) * 128;
#pragma unroll
        for (int r = 0; r < 2; ++r) {
            int f = r * 2048 + t * 8;              // float index, 8 per rep
            uint4 u = *(const uint4*)(hsrc + f);
            float d[8];
            bf8_to_f(u, d);
            int px = f >> 7;
            int sw2 = ((px & 7) << 4) ^ (((px >> 3) & 1) << 6);
            *(float4*)((char*)h2l + ((f * 4) ^ sw2))      = make_float4(d[0], d[1], d[2], d[3]);
            *(float4*)((char*)h2l + ((f * 4 + 16) ^ sw2)) = make_float4(d[4], d[5], d[6], d[7]);
        }
    }
    {   // ybar (verbatim k_yc arithmetic)
        int o = t, w = o >> 2;
        const float* gp = &G[(size_t)(b * 64 + w) * 128];
        float s0 = 0.f, s1 = 0.f, s2 = 0.f, s3 = 0.f;
#pragma unroll 4
        for (int k = 0; k < 128; k += 4) {
            s0 = fmaf(W3psi[(k + 0) * 256 + o], gp[k + 0], s0);
            s1 = fmaf(W3psi[(k + 1) * 256 + o], gp[k + 1], s1);
            s2 = fmaf(W3psi[(k + 2) * 256 + o], gp[k + 2], s2);
            s3 = fmaf(W3psi[(k + 3) * 256 + o], gp[k + 3], s3);
        }
        float s = b3psi[o] * sv[b * 64 + w] + ((s0 + s1) + (s2 + s3));
        ybar[o] = s * (1.f / 16384.f);
    }
    __syncthreads();
#pragma unroll
    for (int rep = 0; rep < 32; ++rep) {
        int e = rep * 256 + t;       // C: 8192 elems (verbatim k_yc arithmetic)
        int w = e >> 7, k = e & 127;
        const float* wp = &W3phi[k * 256 + w * 4];
        cl[e] = fmaf(wp[0], ybar[w * 4],
                fmaf(wp[1], ybar[w * 4 + 1],
                fmaf(wp[2], ybar[w * 4 + 2], wp[3] * ybar[w * 4 + 3])));
    }
    if (t < 64) {
        Dl[t] = b3phi[t * 4] * ybar[t * 4] + b3phi[t * 4 + 1] * ybar[t * 4 + 1]
              + b3phi[t * 4 + 2] * ybar[t * 4 + 2] + b3phi[t * 4 + 3] * ybar[t * 4 + 3];
    }
    __syncthreads();

    int px = t & 31;
    int w0 = (t >> 5) << 3;          // 0..56: 8 w per thread
    int psw = ((px & 7) << 4) ^ (((px >> 3) & 1) << 6);
    float acc[8];
#pragma unroll
    for (int j = 0; j < 8; ++j) acc[j] = 0.f;

#pragma unroll 4
    for (int kq = 0; kq < 32; ++kq) {
        float4 hq = *(float4*)((char*)h2l + ((px * 512 + kq * 16) ^ psw));
#pragma unroll
        for (int j = 0; j < 8; ++j) {
            float4 cq = *(float4*)&cl[(w0 + j) * 128 + kq * 4];
            acc[j] = fmaf(hq.x, cq.x, acc[j]);
            acc[j] = fmaf(hq.y, cq.y, acc[j]);
            acc[j] = fmaf(hq.z, cq.z, acc[j]);
            acc[j] = fmaf(hq.w, cq.w, acc[j]);
        }
    }
    unsigned short us[8];
#pragma unroll
    for (int j = 0; j < 8; ++j) us[j] = f2bf(acc[j] + Dl[w0 + j]);
    unsigned short* op = x2c + ((size_t)(b * 16384 + px0 + px)) * 64 + w0;
    *(uint4*)op = *(uint4*)us;
}

// ---------------- epilogue: h = LN(x1 + up(yl1) + up(yl2) + up(x2c)); bf16 in/out ----------------
__global__ __launch_bounds__(256) void k_epilogue(const unsigned short* __restrict__ x1,
                                                  const unsigned short* __restrict__ yl1,
                                                  const unsigned short* __restrict__ yl2,
                                                  const unsigned short* __restrict__ x2c,
                                                  const float* __restrict__ lnG,
                                                  const float* __restrict__ lnB,
                                                  unsigned short* __restrict__ hbf,
                                                  int do_relu) {
    __shared__ float y1s[2][10][64];   // yl1 corners (scale 2)
    __shared__ float xcs[2][10][64];   // x2c corners (scale 2)
    __shared__ float y2s[2][6][64];    // yl2 corners (scale 4)
    int t    = threadIdx.x;
    int blk  = blockIdx.x;                 // 8192 = 2 * 256 * 16
    int b    = blk >> 12;
    int rest = blk & 4095;
    int y    = rest >> 4;
    int x0   = (rest & 15) << 4;
    int wv = t >> 6, lane = t & 63;

    Lerp ly1 = lcoord(y, 0.5f, -0.25f, 128);    // yl1 & x2c
    Lerp ly2 = lcoord(y, 0.25f, -0.375f, 64);   // yl2
    int c1 = max(0, (int)floorf((float)x0 * 0.5f - 0.25f));
    int c2 = max(0, (int)floorf((float)x0 * 0.25f - 0.375f));

    const unsigned short* Y1 = yl1 + (size_t)b * 16384 * 64;
    const unsigned short* Y2 = yl2 + (size_t)b * 4096 * 64;
    const unsigned short* XC = x2c + (size_t)b * 16384 * 64;
    for (int f4 = t; f4 < 832; f4 += 256) {
        int e, row, col;
        const unsigned short* src;
        float* dst;
        if (f4 < 320) {                 // y1s
            e = f4 * 4;
            int r = e / 640, rm = e - r * 640;
            int j = rm >> 6, ch = rm & 63;
            row = r ? ly1.i1 : ly1.i0;
            col = min(c1 + j, 127);
            src = &Y1[((size_t)(row * 128 + col)) * 64 + ch];
            dst = &y1s[r][j][ch];
        } else if (f4 < 640) {          // xcs
            e = (f4 - 320) * 4;
            int r = e / 640, rm = e - r * 640;
            int j = rm >> 6, ch = rm & 63;
            row = r ? ly1.i1 : ly1.i0;
            col = min(c1 + j, 127);
            src = &XC[((size_t)(row * 128 + col)) * 64 + ch];
            dst = &xcs[r][j][ch];
        } else {                        // y2s
            e = (f4 - 640) * 4;
            int r = e / 384, rm = e - r * 384;
            int j = rm >> 6, ch = rm & 63;
            row = r ? ly2.i1 : ly2.i0;
            col = min(c2 + j, 63);
            src = &Y2[((size_t)(row * 64 + col)) * 64 + ch];
            dst = &y2s[r][j][ch];
        }
        uint2 u = *(const uint2*)src;   // 4 bf16
        dst[0] = __uint_as_float((u.x & 0xFFFFu) << 16);
        dst[1] = __uint_as_float(u.x & 0xFFFF0000u);
        dst[2] = __uint_as_float((u.y & 0xFFFFu) << 16);
        dst[3] = __uint_as_float(u.y & 0xFFFF0000u);
    }
    __syncthreads();

    float g = lnG[lane], be = lnB[lane];
    for (int pp = 0; pp < 4; ++pp) {
        int xx = x0 + wv * 4 + pp;
        size_t pix = (size_t)((b * 256 + y) * 256 + xx);
        float v = bf2f(x1[pix * 64 + lane]);
        {   // yl1 + x2c (shared x-lerp)
            Lerp lx = lcoord(xx, 0.5f, -0.25f, 128);
            int j0 = lx.i0 - c1, j1 = lx.i1 - c1;
            float a0 = y1s[0][j0][lane], a1 = y1s[0][j1][lane];
            float b0 = y1s[1][j0][lane], b1 = y1s[1][j1][lane];
            float ta = a0 + lx.f * (a1 - a0);
            float tb = b0 + lx.f * (b1 - b0);
            v += ta + ly1.f * (tb - ta);
            float p0 = xcs[0][j0][lane], p1 = xcs[0][j1][lane];
            float q0 = xcs[1][j0][lane], q1 = xcs[1][j1][lane];
            float tp = p0 + lx.f * (p1 - p0);
            float tq = q0 + lx.f * (q1 - q0);
            v += tp + ly1.f * (tq - tp);
        }
        {   // yl2
            Lerp lx = lcoord(xx, 0.25f, -0.375f, 64);
            int j0 = lx.i0 - c2, j1 = lx.i1 - c2;
            float a0 = y2s[0][j0][lane], a1 = y2s[0][j1][lane];
            float b0 = y2s[1][j0][lane], b1 = y2s[1][j1][lane];
            float ta = a0 + lx.f * (a1 - a0);
            float tb = b0 + lx.f * (b1 - b0);
            v += ta + ly2.f * (tb - ta);
        }
        float mu  = wave_sum64(v) * (1.f / 64.f);
        float d   = v - mu;
        float var = wave_sum64(d * d) * (1.f / 64.f);
        float ov  = fmaf(d * rsqrtf(var + 1e-5f), g, be);
        if (do_relu) ov = fmaxf(ov, 0.f);
        hbf[pix * 64 + lane] = f2bf(ov);
    }
}

// ---------------- head (MFMA): out = relu(hbf@q1W+q1b) . q2 + q2b ----------------
__global__ __launch_bounds__(256) void k_head_mfma(
    const unsigned short* __restrict__ hbf,   // [131072][64] bf16
    const unsigned short* __restrict__ q1bf,  // [128 j][64 k] bf16
    const float* __restrict__ q1b,            // [128]
    const float* __restrict__ q2,             // [128]
    const float* __restrict__ q2b,            // [1]
    float* __restrict__ out) {
    __shared__ unsigned short Q[8192];        // [j][k] swizzled
    int t = threadIdx.x;
    for (int c = t; c < 1024; c += 256) {
        int j = c >> 3, slot = c & 7;
        uint4 v = *(const uint4*)(q1bf + j * 64 + slot * 8);
        int byte = (j * 128 + slot * 16) ^ ((j & 7) << 4);
        *(uint4*)((char*)Q + byte) = v;
    }
    __syncthreads();

    int w = t >> 6, lane = t & 63;
    int lo = lane & 31, hi = lane >> 5;
    int px0 = blockIdx.x * 128 + w * 32;      // grid 1024

    bf16x8_t av[4];
    const unsigned short* hp = hbf + (size_t)(px0 + lo) * 64 + hi * 8;
#pragma unroll
    for (int ks = 0; ks < 4; ++ks)
        av[ks] = *(const bf16x8_t*)(hp + ks * 16);

    float res[16];
#pragma unroll
    for (int r = 0; r < 16; ++r) res[r] = 0.f;

#pragma unroll
    for (int jb = 0; jb < 4; ++jb) {
        f32x16_t acc = {};
        int j = jb * 32 + lo;
#pragma unroll
        for (int ks = 0; ks < 4; ++ks) {
            int byte = (j * 128 + ks * 32 + hi * 16) ^ ((j & 7) << 4);
            bf16x8_t bv = *(bf16x8_t*)((char*)Q + byte);
            acc = __builtin_amdgcn_mfma_f32_32x32x16_bf16(av[ks], bv, acc, 0, 0, 0);
        }
        float b1 = q1b[j];
        float w2 = q2[j];
#pragma unroll
        for (int r = 0; r < 16; ++r)
            res[r] = fmaf(fmaxf(acc[r] + b1, 0.f), w2, res[r]);
    }
#pragma unroll
    for (int r = 0; r < 16; ++r) {
        float v = res[r];
        v += __shfl_xor(v, 1);
        v += __shfl_xor(v, 2);
        v += __shfl_xor(v, 4);
        v += __shfl_xor(v, 8);
        v += __shfl_xor(v, 16);
        res[r] = v;
    }
    if (lo == 0) {
        float qb = q2b[0];
#pragma unroll
        for (int r = 0; r < 16; ++r) {
            int row = (r & 3) + 8 * (r >> 2) + 4 * hi;
            out[px0 + row] = res[r] + qb;
        }
    }
}

// ---------------- launch ----------------
extern "C" void kernel_launch(void* const* d_in, const int* in_sizes, int n_in,
                              void* d_out, int out_size, void* d_ws, size_t ws_size,
                              hipStream_t stream) {
    const float* x     = (const float*)d_in[0];
    const float* a     = (const float*)d_in[1];
    const float* pW    = (const float*)d_in[2];
    const float* pb    = (const float*)d_in[3];
    const float* q1W   = (const float*)d_in[4];
    const float* q1b   = (const float*)d_in[5];
    const float* q2W   = (const float*)d_in[6];
    const float* q2b   = (const float*)d_in[7];
    const float* phiW1 = (const float*)d_in[8];
    const float* phib1 = (const float*)d_in[9];
    const float* phiW2 = (const float*)d_in[10];
    const float* phib2 = (const float*)d_in[11];
    const float* phiW3 = (const float*)d_in[12];
    const float* phib3 = (const float*)d_in[13];
    const float* psiW1 = (const float*)d_in[14];
    const float* psib1 = (const float*)d_in[15];
    const float* psiW2 = (const float*)d_in[16];
    const float* psib2 = (const float*)d_in[17];
    const float* psiW3 = (const float*)d_in[18];
    const float* psib3 = (const float*)d_in[19];
    const float* lnG   = (const float*)d_in[20];
    const float* lnB   = (const float*)d_in[21];
    const float* convW = (const float*)d_in[22];
    const float* convb = (const float*)d_in[23];

    float* ws = (float*)d_ws;
    unsigned short* x1    = (unsigned short*)(ws + OFF_X1);
    unsigned short* yl1   = (unsigned short*)(ws + OFF_YL1);
    unsigned short* yl2   = (unsigned short*)(ws + OFF_YL2);
    unsigned short* hbf   = (unsigned short*)(ws + OFF_HBF);
    unsigned short* H2psi = (unsigned short*)(ws + OFF_H2PSI);
    unsigned short* x2c   = (unsigned short*)(ws + OFF_H2PSI);  // overlay: H2psi dead after k_gpart
    unsigned short* H2phi = (unsigned short*)(ws + OFF_H2PHI);
    unsigned short* cwtbf = (unsigned short*)(ws + OFF_CWTBF);
    unsigned short* q1bf  = (unsigned short*)(ws + OFF_Q1BF);
    unsigned short* w2t   = (unsigned short*)(ws + OFF_W2T);
    float* Gpart = ws + OFF_GPART;
    float* svpart= ws + OFF_SVP;
    float* G     = ws + OFF_G;
    float* sv    = ws + OFF_SV;

    k_setup<<<2528, 256, 0, stream>>>(convW, cwtbf, q1W, q1bf,
                                      psiW2, phiW2, w2t, x, a, pW, pb, hbf);

    for (int i = 0; i < 4; ++i) {
        k_convmlp<<<1696, 256, 0, stream>>>(hbf, cwtbf, convb, x1, yl1, yl2,
                                            a, x,
                                            psiW1 + i * 192, psib1 + i * 64, psib2 + i * 128,
                                            phiW1 + i * 192, phib1 + i * 64, phib2 + i * 128,
                                            w2t, H2psi, H2phi, i);
        k_gpart<<<512, 256, 0, stream>>>(hbf, H2psi, Gpart, svpart);
        k_gred<<<258, 256, 0, stream>>>(Gpart, svpart, G, sv);
        k_x2cyc<<<1024, 256, 0, stream>>>(G, sv,
                                          psiW3 + (size_t)i * 32768, psib3 + i * 256,
                                          phiW3 + (size_t)i * 32768, phib3 + i * 256,
                                          H2phi, x2c);
        k_epilogue<<<8192, 256, 0, stream>>>(x1, yl1, yl2, x2c,
                                             lnG + i * 64, lnB + i * 64,
                                             hbf, (i < 3) ? 1 : 0);
    }

    k_head_mfma<<<1024, 256, 0, stream>>>(hbf, q1bf, q1b, q2W, q2b, (float*)d_out);
}

// Round 18
// 426.452 us; speedup vs baseline: 1.1000x; 1.1000x over previous
//
#include <hip/hip_runtime.h>
#include <cstddef>
#include <cstdint>

// ---------------- problem constants ----------------
// b=2, s=256, WIDTH=64, RANK=4, CLEVEL=1 (c=2), MLEVEL=2 (L=3), NB=4
// HID1=64, HID2=128

// ---------------- workspace layout (float-slot offsets) ----------------
// x1/yl1/yl2/x2c/H2psi/H2phi/h are bf16.
static constexpr size_t OFF_X1     = 0;          // bf16 2*256*256*64 -> 4194304 slots
static constexpr size_t OFF_YL1    = 4194304;    // bf16 -> 1048576
static constexpr size_t OFF_YL2    = 5242880;    // bf16 -> 262144
static constexpr size_t OFF_HBF    = 5505024;    // bf16 h -> 4194304
static constexpr size_t OFF_H2PSI  = 9699328;    // bf16 32768*128 -> 2097152 (x2c overlays)
static constexpr size_t OFF_H2PHI  = 11796480;   // 2097152
static constexpr size_t OFF_CWTBF  = 13893632;   // 221184
static constexpr size_t OFF_Q1BF   = 14114816;   // 4096
static constexpr size_t OFF_W2T    = 14118912;   // 8*8192 bf16 = 32768 float-slots
static constexpr size_t OFF_GPART  = 14151680;   // 512*8192 f32 = 4194304
static constexpr size_t OFF_SVP    = 18345984;   // 32768
static constexpr size_t OFF_G      = 18378752;   // 16384
static constexpr size_t OFF_SV     = 18395136;   // 128
static constexpr size_t OFF_C      = 18395264;   // 16384
static constexpr size_t OFF_D      = 18411648;   // 128
// end = 18411776 floats (~73.6 MB) <= proven-available 134.3 MB

typedef __attribute__((ext_vector_type(8)))  short bf16x8_t;   // 8 bf16 in 4 VGPRs
typedef __attribute__((ext_vector_type(16))) float f32x16_t;   // 32x32 MFMA acc

// ---------------- helpers ----------------
__device__ inline float wave_sum64(float v) {
    v += __shfl_xor(v, 1);
    v += __shfl_xor(v, 2);
    v += __shfl_xor(v, 4);
    v += __shfl_xor(v, 8);
    v += __shfl_xor(v, 16);
    v += __shfl_xor(v, 32);
    return v;
}

__device__ inline unsigned short f2bf(float f) {   // round-to-nearest-even
    uint32_t u = __float_as_uint(f);
    uint32_t r = u + 0x7FFFu + ((u >> 16) & 1u);
    return (unsigned short)(r >> 16);
}
__device__ inline float bf2f(unsigned short u) {
    return __uint_as_float((uint32_t)u << 16);
}
// 8 bf16 (uint4) -> 8 f32
__device__ inline void bf8_to_f(uint4 u, float* d) {
    unsigned uv[4] = {u.x, u.y, u.z, u.w};
#pragma unroll
    for (int i = 0; i < 4; ++i) {
        d[2 * i]     = __uint_as_float((uv[i] & 0xFFFFu) << 16);
        d[2 * i + 1] = __uint_as_float(uv[i] & 0xFFFF0000u);
    }
}

// full-res flat pixel index of coarse pixel (b, n): n in [0,16384)
__device__ inline size_t fullpix(int b, int n) {
    return (size_t)(b * 65536 + (n >> 7) * 512 + ((n & 127) << 1));
}

struct Lerp { int i0, i1; float f; };
__device__ inline Lerp lcoord(int o, float r, float off, int Sin) {
    float s = fmaxf(fmaf((float)o, r, off), 0.f);
    Lerp L;
    L.i0 = (int)s;
    L.f  = s - (float)L.i0;
    L.i1 = min(L.i0 + 1, Sin - 1);
    return L;
}

// ---------------- fused setup: convW | q1 | W2 frag-order | lift ----------------
// grid 2528: [0,1728) convW; [1728,1760) q1; [1760,2016) W2t; [2016,2528) lift
__global__ __launch_bounds__(256) void k_setup(const float* __restrict__ convW,
                                               unsigned short* __restrict__ cwt,
                                               const float* __restrict__ q1W,
                                               unsigned short* __restrict__ q1bf,
                                               const float* __restrict__ psiW2,
                                               const float* __restrict__ phiW2,
                                               unsigned short* __restrict__ w2t,
                                               const float* __restrict__ x,
                                               const float* __restrict__ a,
                                               const float* __restrict__ pW,
                                               const float* __restrict__ pb,
                                               unsigned short* __restrict__ hbf) {
    int bid = blockIdx.x;
    int t = threadIdx.x;
    if (bid < 1728) {
        // convW[i][l][oc][ic][3][3] f32 -> wt[((il*9+tap)*4+kq)*1024 + hi*512 + oc*8 + j]
        int idx = bid * 256 + t;                  // 442368
        if (idx >= 442368) return;
        int j    = idx & 7;
        int oc   = (idx >> 3) & 63;
        int hi   = (idx >> 9) & 1;
        int kq   = (idx >> 10) & 3;
        int rest = idx >> 12;                     // il*9 + tap
        int tap  = rest % 9;
        int il   = rest / 9;
        int ic   = kq * 16 + hi * 8 + j;
        cwt[idx] = f2bf(convW[((size_t)(il * 64 + oc) * 64 + ic) * 9 + tap]);
    } else if (bid < 1760) {
        int idx = (bid - 1728) * 256 + t;         // 8192
        int k = idx & 63;
        int j = idx >> 6;
        q1bf[j * 64 + k] = f2bf(q1W[k * 128 + j]);
    } else if (bid < 2016) {
        // W2[m][i][64 k][128 j] -> w2t[((((m*4+i)*4+jt)*4+kq)*2+hi)*256 + lo*8 + jj]
        int idx = (bid - 1760) * 256 + t;         // 65536
        int jj = idx & 7;
        int lo = (idx >> 3) & 31;
        int hi = (idx >> 8) & 1;
        int kq = (idx >> 9) & 3;
        int jt = (idx >> 11) & 3;
        int i  = (idx >> 13) & 3;
        int m  = idx >> 15;
        int k  = kq * 16 + hi * 8 + jj;
        int j  = jt * 32 + lo;
        const float* W2 = m ? phiW2 : psiW2;
        w2t[idx] = f2bf(W2[(size_t)i * 8192 + k * 128 + j]);
    } else {
        int p = (bid - 2016) * 256 + t;           // 131072
        float a0 = a[(size_t)p * 2 + 0];
        float a1 = a[(size_t)p * 2 + 1];
        float xv = x[p];
        float vals[64];
#pragma unroll
        for (int c = 0; c < 64; ++c)
            vals[c] = fmaf(a0, pW[c], fmaf(a1, pW[64 + c], fmaf(xv, pW[128 + c], pb[c])));
        unsigned short us[64];
#pragma unroll
        for (int c = 0; c < 64; ++c) us[c] = f2bf(vals[c]);
        unsigned short* bp = hbf + (size_t)p * 64;
#pragma unroll
        for (int c = 0; c < 64; c += 8)
            *(uint4*)(bp + c) = *(uint4*)(us + c);
    }
}

// ---------------- fused conv (blocks 0..671) + mlp-MFMA (blocks 672..1695) ----------------
// conv: A-only LDS, frag-order B from L2 (reg dbuf), direct bf16 stores.
// mlp:  h1 per-lane + W2-GEMM via MFMA; outputs bf16.
__global__ __launch_bounds__(256) void k_convmlp(
    const unsigned short* __restrict__ hbf,   // [2][256][256][64] bf16
    const unsigned short* __restrict__ wbf,   // conv W frag-order, 36864 per (iter,lvl)
    const float* __restrict__ convb,          // [12][64]
    unsigned short* __restrict__ x1, unsigned short* __restrict__ yl1,
    unsigned short* __restrict__ yl2,
    const float* __restrict__ a, const float* __restrict__ x,
    const float* __restrict__ W1a, const float* __restrict__ b1a,
    const float* __restrict__ b2a,
    const float* __restrict__ W1b, const float* __restrict__ b1b,
    const float* __restrict__ b2b,
    const unsigned short* __restrict__ w2t,   // mlp W2 frag-order
    unsigned short* __restrict__ H2a, unsigned short* __restrict__ H2b,
    int iter) {
    __shared__ unsigned short Ald[20736];     // 324 px * 64 ic (41472 B) — conv path only
    int bid = blockIdx.x;
    int t = threadIdx.x;

    if (bid >= 672) {
        // ---------------- mlp path (MFMA) ----------------
        int blk = bid - 672;                       // 0..1023
        int m = blk >> 9;                          // 0=psi, 1=phi
        int px0 = (blk & 511) << 6;                // 64 px per block
        const float* W1 = m ? W1b : W1a;
        const float* b1 = m ? b1b : b1a;
        const float* b2 = m ? b2b : b2a;
        unsigned short* H2 = m ? H2b : H2a;

        int w    = t >> 6;                         // j-tile 0..3
        int lane = t & 63;
        int lo   = lane & 31;
        int hi   = lane >> 5;

        int pxlA = px0 + lo, pxlB = px0 + 32 + lo;
        int bA = pxlA >> 14;
        size_t apA = fullpix(bA, pxlA & 16383);
        size_t apB = fullpix(bA, pxlB & 16383);
        float a0A = a[apA * 2], a1A = a[apA * 2 + 1], xvA = x[apA];
        float a0B = a[apB * 2], a1B = a[apB * 2 + 1], xvB = x[apB];

        bf16x8_t faA[4], faB[4];
#pragma unroll
        for (int kq = 0; kq < 4; ++kq) {
            unsigned short tA[8], tB[8];
#pragma unroll
            for (int jj = 0; jj < 8; ++jj) {
                int k = kq * 16 + hi * 8 + jj;
                float w1a = W1[k], w1b = W1[64 + k], w1c = W1[128 + k], bb = b1[k];
                tA[jj] = f2bf(fmaxf(fmaf(a0A, w1a, fmaf(a1A, w1b, fmaf(xvA, w1c, bb))), 0.f));
                tB[jj] = f2bf(fmaxf(fmaf(a0B, w1a, fmaf(a1B, w1b, fmaf(xvB, w1c, bb))), 0.f));
            }
            faA[kq] = *(bf16x8_t*)tA;
            faB[kq] = *(bf16x8_t*)tB;
        }
        const unsigned short* wb =
            w2t + (size_t)(((m * 4 + iter) * 4 + w) * 4) * 512 + hi * 256 + lo * 8;
        f32x16_t accA = {}, accB = {};
#pragma unroll
        for (int kq = 0; kq < 4; ++kq) {
            bf16x8_t fb = *(const bf16x8_t*)(wb + kq * 512);
            accA = __builtin_amdgcn_mfma_f32_32x32x16_bf16(faA[kq], fb, accA, 0, 0, 0);
            accB = __builtin_amdgcn_mfma_f32_32x32x16_bf16(faB[kq], fb, accB, 0, 0, 0);
        }
        float bias2 = b2[w * 32 + lo];
#pragma unroll
        for (int reg = 0; reg < 16; ++reg) {
            int row = (reg & 3) + 8 * (reg >> 2) + 4 * hi;
            H2[(size_t)(px0 + row) * 128 + w * 32 + lo]      = f2bf(fmaxf(accA[reg] + bias2, 0.f));
            H2[(size_t)(px0 + 32 + row) * 128 + w * 32 + lo] = f2bf(fmaxf(accB[reg] + bias2, 0.f));
        }
        return;
    }

    // ---------------- conv path ----------------
    int lvl, tix, Sl, st, tpr;
    if (bid < 512)      { lvl = 0; tix = bid;       Sl = 256; st = 1; tpr = 16; }
    else if (bid < 640) { lvl = 1; tix = bid - 512; Sl = 128; st = 2; tpr = 8;  }
    else                { lvl = 2; tix = bid - 640; Sl = 64;  st = 4; tpr = 4;  }
    int tpb = tpr * tpr;
    int b = tix / tpb;
    int r = tix - b * tpb;
    int y0 = (r / tpr) * 16, x0 = (r % tpr) * 16;

    // ---- stage A: 18x18 halo x 64 ic, zero-padded ----
    for (int c = t; c < 2592; c += 256) {
        int lin = c >> 3, slot = c & 7;
        int ty = lin / 18, tx = lin - ty * 18;
        int oy = y0 + ty - 1, ox = x0 + tx - 1;
        uint4 val = make_uint4(0u, 0u, 0u, 0u);
        if ((unsigned)oy < (unsigned)Sl && (unsigned)ox < (unsigned)Sl) {
            const unsigned short* src =
                hbf + (((size_t)(b * 256 + oy * st) * 256 + ox * st) << 6) + (slot << 3);
            val = *(const uint4*)src;
        }
        int byte = (lin << 7) + (((slot ^ (lin & 7))) << 4);
        *(uint4*)((char*)Ald + byte) = val;
    }
    __syncthreads();

    int w    = t >> 6;
    int lane = t & 63;
    int lo   = lane & 31;
    int hi   = lane >> 5;
    f32x16_t acc00 = {}, acc01 = {}, acc10 = {}, acc11 = {};

    const unsigned short* wbase =
        wbf + (size_t)(iter * 3 + lvl) * 36864 + hi * 512 + lo * 8;

    int yA0 = 4 * w + (lo >> 4);
    int xA  = lo & 15;

    bf16x8_t v0c[4], v1c[4], v0n[4], v1n[4];
#pragma unroll
    for (int kq = 0; kq < 4; ++kq) {
        v0c[kq] = *(const bf16x8_t*)(wbase + kq * 1024);
        v1c[kq] = *(const bf16x8_t*)(wbase + kq * 1024 + 256);
    }
#pragma unroll
    for (int tap = 0; tap < 9; ++tap) {
        if (tap < 8) {
#pragma unroll
            for (int kq = 0; kq < 4; ++kq) {
                int keo = ((tap + 1) * 4 + kq) * 1024;
                v0n[kq] = *(const bf16x8_t*)(wbase + keo);
                v1n[kq] = *(const bf16x8_t*)(wbase + keo + 256);
            }
        }
        int dy = tap / 3, dx = tap - dy * 3;
        int lin0 = (yA0 + dy) * 18 + (xA + dx);
        int lin1 = lin0 + 36;
#pragma unroll
        for (int kq = 0; kq < 4; ++kq) {
            int icb = (kq << 5) + (hi << 4);            // byte offset in A row
            int a0b = ((lin0 << 7) + icb) ^ ((lin0 & 7) << 4);
            int a1b = ((lin1 << 7) + icb) ^ ((lin1 & 7) << 4);
            bf16x8_t va0 = *(bf16x8_t*)((char*)Ald + a0b);
            bf16x8_t va1 = *(bf16x8_t*)((char*)Ald + a1b);
            acc00 = __builtin_amdgcn_mfma_f32_32x32x16_bf16(va0, v0c[kq], acc00, 0, 0, 0);
            acc01 = __builtin_amdgcn_mfma_f32_32x32x16_bf16(va0, v1c[kq], acc01, 0, 0, 0);
            acc10 = __builtin_amdgcn_mfma_f32_32x32x16_bf16(va1, v0c[kq], acc10, 0, 0, 0);
            acc11 = __builtin_amdgcn_mfma_f32_32x32x16_bf16(va1, v1c[kq], acc11, 0, 0, 0);
        }
#pragma unroll
        for (int kq = 0; kq < 4; ++kq) { v0c[kq] = v0n[kq]; v1c[kq] = v1n[kq]; }
    }

    // ---- store bf16 (C layout: col=lo -> oc, row=(reg&3)+8*(reg>>2)+4*hi -> pixel) ----
    unsigned short* out = (lvl == 0) ? x1 : (lvl == 1 ? yl1 : yl2);
    const float* bias = convb + (iter * 3 + lvl) * 64;
    float bias0 = bias[lo];
    float bias1 = bias[32 + lo];
#pragma unroll
    for (int reg = 0; reg < 16; ++reg) {
        int row = (reg & 3) + 8 * (reg >> 2) + 4 * hi;
        int yt  = 4 * w + (row >> 4);
        int xt  = row & 15;
        size_t pix0 = ((size_t)(b * Sl + y0 + yt) * Sl + (x0 + xt)) << 6;
        out[pix0 + lo]      = f2bf(acc00[reg] + bias0);
        out[pix0 + 32 + lo] = f2bf(acc01[reg] + bias1);
        size_t pix1 = ((size_t)(b * Sl + y0 + yt + 2) * Sl + (x0 + xt)) << 6;
        out[pix1 + lo]      = f2bf(acc10[reg] + bias0);
        out[pix1 + 32 + lo] = f2bf(acc11[reg] + bias1);
    }
}

// ---------------- split-K stage 1: Gpart[blk] = v^T H2psi over 64 px; svpart ----------------
__global__ __launch_bounds__(256) void k_gpart(const unsigned short* __restrict__ hbf,
                                               const unsigned short* __restrict__ H2psi,
                                               float* __restrict__ Gpart,
                                               float* __restrict__ svpart) {
    __shared__ float vt[4096];       // [64 px][64 w]
    __shared__ float h2t[8192];      // [64 px][128 j]
    int blk = blockIdx.x;            // 512
    int b = blk >> 8;
    int n0 = (blk & 255) << 6;
    int t = threadIdx.x;
    int pxq = t >> 2, qq = t & 3;
    int sw = (pxq & 7) << 4;
    {
        const unsigned short* src = hbf + fullpix(b, n0 + pxq) * 64 + qq * 16;
        uint4 u0 = *(const uint4*)src;
        uint4 u1 = *(const uint4*)(src + 8);
        float f[16];
        bf8_to_f(u0, f);
        bf8_to_f(u1, f + 8);
#pragma unroll
        for (int j = 0; j < 4; ++j) {
            int byte = (pxq * 256 + qq * 64 + j * 16) ^ sw;
            *(float4*)((char*)vt + byte) = make_float4(f[4 * j], f[4 * j + 1],
                                                       f[4 * j + 2], f[4 * j + 3]);
        }
        const unsigned short* hsrc = H2psi + ((size_t)(b * 16384 + n0 + pxq)) * 128 + qq * 32;
#pragma unroll
        for (int rr = 0; rr < 4; ++rr) {
            uint4 hu = *(const uint4*)(hsrc + rr * 8);
            float g[8];
            bf8_to_f(hu, g);
            int byte0 = (pxq * 512 + qq * 128 + rr * 32) ^ sw;
            int byte1 = (pxq * 512 + qq * 128 + rr * 32 + 16) ^ sw;
            *(float4*)((char*)h2t + byte0) = make_float4(g[0], g[1], g[2], g[3]);
            *(float4*)((char*)h2t + byte1) = make_float4(g[4], g[5], g[6], g[7]);
        }
    }
    __syncthreads();

    int wt_ = (t >> 5) << 3;         // 0..56
    int kt  = (t & 31) << 2;         // 0..124
    float acc[8][4];
#pragma unroll
    for (int i = 0; i < 8; ++i)
#pragma unroll
        for (int j = 0; j < 4; ++j) acc[i][j] = 0.f;

#pragma unroll 4
    for (int nn = 0; nn < 64; ++nn) {
        int nsw = (nn & 7) << 4;
        float4 hv = *(float4*)((char*)h2t + ((nn * 512 + kt * 4) ^ nsw));
        float4 v0 = *(float4*)((char*)vt + ((nn * 256 + wt_ * 4) ^ nsw));
        float4 v1 = *(float4*)((char*)vt + ((nn * 256 + wt_ * 4 + 16) ^ nsw));
        float vv[8] = {v0.x, v0.y, v0.z, v0.w, v1.x, v1.y, v1.z, v1.w};
        float hh[4] = {hv.x, hv.y, hv.z, hv.w};
#pragma unroll
        for (int i = 0; i < 8; ++i)
#pragma unroll
            for (int j = 0; j < 4; ++j) acc[i][j] = fmaf(vv[i], hh[j], acc[i][j]);
    }

    float* gp = Gpart + (size_t)blk * 8192;
#pragma unroll
    for (int i = 0; i < 8; ++i)
        *(float4*)&gp[(wt_ + i) * 128 + kt] =
            make_float4(acc[i][0], acc[i][1], acc[i][2], acc[i][3]);

    if (t < 64) {
        float s = 0.f;
#pragma unroll 8
        for (int p = 0; p < 64; ++p)
            s += *(float*)((char*)vt + ((p * 256 + t * 4) ^ ((p & 7) << 4)));
        svpart[blk * 64 + t] = s;
    }
}

// ---------------- reduce: G = sum Gpart; sv = sum svpart (grid 258) ----------------
__global__ __launch_bounds__(256) void k_gred(const float* __restrict__ Gpart,
                                              const float* __restrict__ svpart,
                                              float* __restrict__ G,
                                              float* __restrict__ sv) {
    __shared__ float red[4][64];
    int blk = blockIdx.x;
    int t = threadIdx.x;
    if (blk < 256) {
        int b  = blk >> 7;
        int es = (blk & 127) << 6;
        int e  = es + (t & 63);
        int cg = t >> 6;
        float s = 0.f;
        const float* gp = Gpart + ((size_t)(b * 256 + cg * 64)) * 8192 + e;
#pragma unroll 8
        for (int c = 0; c < 64; ++c) s += gp[(size_t)c * 8192];
        red[cg][t & 63] = s;
        __syncthreads();
        if (t < 64)
            G[b * 8192 + es + t] = red[0][t] + red[1][t] + red[2][t] + red[3][t];
    } else {
        int b = blk - 256;
        int w = t & 63, cg = t >> 6;
        float s = 0.f;
        const float* sp = svpart + ((size_t)(b * 256 + cg * 64)) * 64 + w;
#pragma unroll 8
        for (int c = 0; c < 64; ++c) s += sp[c * 64];
        red[cg][w] = s;
        __syncthreads();
        if (t < 64) sv[b * 64 + t] = red[0][t] + red[1][t] + red[2][t] + red[3][t];
    }
}

// ---------------- yc: ybar -> C[b][w][k], D[b][w] (grid 32) ----------------
__global__ __launch_bounds__(256) void k_yc(const float* __restrict__ G,
                                            const float* __restrict__ sv,
                                            const float* __restrict__ W3psi,
                                            const float* __restrict__ b3psi,
                                            const float* __restrict__ W3phi,
                                            const float* __restrict__ b3phi,
                                            float* __restrict__ C,
                                            float* __restrict__ D) {
    __shared__ float ybar[256];
    int bq = blockIdx.x;             // 32
    int b = bq >> 4, q = bq & 15;
    int t = threadIdx.x;
    {
        int o = t, w = o >> 2;
        const float* gp = &G[(size_t)(b * 64 + w) * 128];
        float s0 = 0.f, s1 = 0.f, s2 = 0.f, s3 = 0.f;
#pragma unroll 4
        for (int k = 0; k < 128; k += 4) {
            s0 = fmaf(W3psi[(k + 0) * 256 + o], gp[k + 0], s0);
            s1 = fmaf(W3psi[(k + 1) * 256 + o], gp[k + 1], s1);
            s2 = fmaf(W3psi[(k + 2) * 256 + o], gp[k + 2], s2);
            s3 = fmaf(W3psi[(k + 3) * 256 + o], gp[k + 3], s3);
        }
        float s = b3psi[o] * sv[b * 64 + w] + ((s0 + s1) + (s2 + s3));
        ybar[o] = s * (1.f / 16384.f);
    }
    __syncthreads();
#pragma unroll
    for (int rep = 0; rep < 2; ++rep) {
        int e = q * 512 + rep * 256 + t;   // slice of 8192
        int w = e >> 7, k = e & 127;
        const float* wp = &W3phi[k * 256 + w * 4];
        C[b * 8192 + e] = fmaf(wp[0], ybar[w * 4],
                          fmaf(wp[1], ybar[w * 4 + 1],
                          fmaf(wp[2], ybar[w * 4 + 2], wp[3] * ybar[w * 4 + 3])));
    }
    if (q == 0 && t < 64) {
        int w = t;
        D[b * 64 + w] = b3phi[w * 4] * ybar[w * 4] + b3phi[w * 4 + 1] * ybar[w * 4 + 1]
                      + b3phi[w * 4 + 2] * ybar[w * 4 + 2] + b3phi[w * 4 + 3] * ybar[w * 4 + 3];
    }
}

// ---------------- x2c: x2c[px][w] = H2phi[px][:].C[b][w][:] + D[b][w] (grid 1024) ----------------
__global__ __launch_bounds__(256) void k_x2c(const unsigned short* __restrict__ H2phi,
                                             const float* __restrict__ C,
                                             const float* __restrict__ D,
                                             unsigned short* __restrict__ x2c) {
    __shared__ float cl[8192];       // C[b]: [64 w][128 k] (32 KB)
    __shared__ float h2l[4096];      // [32 px][128 k], XOR-swizzled (16 KB)
    __shared__ float Dl[64];
    int blk = blockIdx.x;            // 1024: 512 per b
    int b = blk >> 9;
    int px0 = (blk & 511) << 5;      // 32 px per block
    int t = threadIdx.x;

    const float* cp = C + b * 8192;
#pragma unroll
    for (int r = 0; r < 8; ++r) {
        int f = r * 1024 + t * 4;
        *(float4*)&cl[f] = *(const float4*)&cp[f];
    }
    if (t < 64) Dl[t] = D[b * 64 + t];
    {   // stage H2phi tile (bf16 -> f32), swizzled
        const unsigned short* hsrc = H2phi + ((size_t)(b * 16384 + px0)) * 128;
#pragma unroll
        for (int r = 0; r < 2; ++r) {
            int f = r * 2048 + t * 8;              // float index, 8 per rep
            uint4 u = *(const uint4*)(hsrc + f);
            float d[8];
            bf8_to_f(u, d);
            int px = f >> 7;
            int sw2 = ((px & 7) << 4) ^ (((px >> 3) & 1) << 6);
            *(float4*)((char*)h2l + ((f * 4) ^ sw2))      = make_float4(d[0], d[1], d[2], d[3]);
            *(float4*)((char*)h2l + ((f * 4 + 16) ^ sw2)) = make_float4(d[4], d[5], d[6], d[7]);
        }
    }
    __syncthreads();

    int px = t & 31;
    int w0 = (t >> 5) << 3;          // 0..56: 8 w per thread
    int psw = ((px & 7) << 4) ^ (((px >> 3) & 1) << 6);
    float acc[8];
#pragma unroll
    for (int j = 0; j < 8; ++j) acc[j] = 0.f;

#pragma unroll 4
    for (int kq = 0; kq < 32; ++kq) {
        float4 hq = *(float4*)((char*)h2l + ((px * 512 + kq * 16) ^ psw));
#pragma unroll
        for (int j = 0; j < 8; ++j) {
            float4 cq = *(float4*)&cl[(w0 + j) * 128 + kq * 4];
            acc[j] = fmaf(hq.x, cq.x, acc[j]);
            acc[j] = fmaf(hq.y, cq.y, acc[j]);
            acc[j] = fmaf(hq.z, cq.z, acc[j]);
            acc[j] = fmaf(hq.w, cq.w, acc[j]);
        }
    }
    unsigned short us[8];
#pragma unroll
    for (int j = 0; j < 8; ++j) us[j] = f2bf(acc[j] + Dl[w0 + j]);
    unsigned short* op = x2c + ((size_t)(b * 16384 + px0 + px)) * 64 + w0;
    *(uint4*)op = *(uint4*)us;
}

// ---------------- epilogue: h = LN(x1 + up(yl1) + up(yl2) + up(x2c)); bf16 in/out ----------------
__global__ __launch_bounds__(256) void k_epilogue(const unsigned short* __restrict__ x1,
                                                  const unsigned short* __restrict__ yl1,
                                                  const unsigned short* __restrict__ yl2,
                                                  const unsigned short* __restrict__ x2c,
                                                  const float* __restrict__ lnG,
                                                  const float* __restrict__ lnB,
                                                  unsigned short* __restrict__ hbf,
                                                  int do_relu) {
    __shared__ float y1s[2][10][64];   // yl1 corners (scale 2)
    __shared__ float xcs[2][10][64];   // x2c corners (scale 2)
    __shared__ float y2s[2][6][64];    // yl2 corners (scale 4)
    int t    = threadIdx.x;
    int blk  = blockIdx.x;                 // 8192 = 2 * 256 * 16
    int b    = blk >> 12;
    int rest = blk & 4095;
    int y    = rest >> 4;
    int x0   = (rest & 15) << 4;
    int wv = t >> 6, lane = t & 63;

    Lerp ly1 = lcoord(y, 0.5f, -0.25f, 128);    // yl1 & x2c
    Lerp ly2 = lcoord(y, 0.25f, -0.375f, 64);   // yl2
    int c1 = max(0, (int)floorf((float)x0 * 0.5f - 0.25f));
    int c2 = max(0, (int)floorf((float)x0 * 0.25f - 0.375f));

    const unsigned short* Y1 = yl1 + (size_t)b * 16384 * 64;
    const unsigned short* Y2 = yl2 + (size_t)b * 4096 * 64;
    const unsigned short* XC = x2c + (size_t)b * 16384 * 64;
    for (int f4 = t; f4 < 832; f4 += 256) {
        int e, row, col;
        const unsigned short* src;
        float* dst;
        if (f4 < 320) {                 // y1s
            e = f4 * 4;
            int r = e / 640, rm = e - r * 640;
            int j = rm >> 6, ch = rm & 63;
            row = r ? ly1.i1 : ly1.i0;
            col = min(c1 + j, 127);
            src = &Y1[((size_t)(row * 128 + col)) * 64 + ch];
            dst = &y1s[r][j][ch];
        } else if (f4 < 640) {          // xcs
            e = (f4 - 320) * 4;
            int r = e / 640, rm = e - r * 640;
            int j = rm >> 6, ch = rm & 63;
            row = r ? ly1.i1 : ly1.i0;
            col = min(c1 + j, 127);
            src = &XC[((size_t)(row * 128 + col)) * 64 + ch];
            dst = &xcs[r][j][ch];
        } else {                        // y2s
            e = (f4 - 640) * 4;
            int r = e / 384, rm = e - r * 384;
            int j = rm >> 6, ch = rm & 63;
            row = r ? ly2.i1 : ly2.i0;
            col = min(c2 + j, 63);
            src = &Y2[((size_t)(row * 64 + col)) * 64 + ch];
            dst = &y2s[r][j][ch];
        }
        uint2 u = *(const uint2*)src;   // 4 bf16
        dst[0] = __uint_as_float((u.x & 0xFFFFu) << 16);
        dst[1] = __uint_as_float(u.x & 0xFFFF0000u);
        dst[2] = __uint_as_float((u.y & 0xFFFFu) << 16);
        dst[3] = __uint_as_float(u.y & 0xFFFF0000u);
    }
    __syncthreads();

    float g = lnG[lane], be = lnB[lane];
    for (int pp = 0; pp < 4; ++pp) {
        int xx = x0 + wv * 4 + pp;
        size_t pix = (size_t)((b * 256 + y) * 256 + xx);
        float v = bf2f(x1[pix * 64 + lane]);
        {   // yl1 + x2c (shared x-lerp)
            Lerp lx = lcoord(xx, 0.5f, -0.25f, 128);
            int j0 = lx.i0 - c1, j1 = lx.i1 - c1;
            float a0 = y1s[0][j0][lane], a1 = y1s[0][j1][lane];
            float b0 = y1s[1][j0][lane], b1 = y1s[1][j1][lane];
            float ta = a0 + lx.f * (a1 - a0);
            float tb = b0 + lx.f * (b1 - b0);
            v += ta + ly1.f * (tb - ta);
            float p0 = xcs[0][j0][lane], p1 = xcs[0][j1][lane];
            float q0 = xcs[1][j0][lane], q1 = xcs[1][j1][lane];
            float tp = p0 + lx.f * (p1 - p0);
            float tq = q0 + lx.f * (q1 - q0);
            v += tp + ly1.f * (tq - tp);
        }
        {   // yl2
            Lerp lx = lcoord(xx, 0.25f, -0.375f, 64);
            int j0 = lx.i0 - c2, j1 = lx.i1 - c2;
            float a0 = y2s[0][j0][lane], a1 = y2s[0][j1][lane];
            float b0 = y2s[1][j0][lane], b1 = y2s[1][j1][lane];
            float ta = a0 + lx.f * (a1 - a0);
            float tb = b0 + lx.f * (b1 - b0);
            v += ta + ly2.f * (tb - ta);
        }
        float mu  = wave_sum64(v) * (1.f / 64.f);
        float d   = v - mu;
        float var = wave_sum64(d * d) * (1.f / 64.f);
        float ov  = fmaf(d * rsqrtf(var + 1e-5f), g, be);
        if (do_relu) ov = fmaxf(ov, 0.f);
        hbf[pix * 64 + lane] = f2bf(ov);
    }
}

// ---------------- head (MFMA): out = relu(hbf@q1W+q1b) . q2 + q2b ----------------
__global__ __launch_bounds__(256) void k_head_mfma(
    const unsigned short* __restrict__ hbf,   // [131072][64] bf16
    const unsigned short* __restrict__ q1bf,  // [128 j][64 k] bf16
    const float* __restrict__ q1b,            // [128]
    const float* __restrict__ q2,             // [128]
    const float* __restrict__ q2b,            // [1]
    float* __restrict__ out) {
    __shared__ unsigned short Q[8192];        // [j][k] swizzled
    int t = threadIdx.x;
    for (int c = t; c < 1024; c += 256) {
        int j = c >> 3, slot = c & 7;
        uint4 v = *(const uint4*)(q1bf + j * 64 + slot * 8);
        int byte = (j * 128 + slot * 16) ^ ((j & 7) << 4);
        *(uint4*)((char*)Q + byte) = v;
    }
    __syncthreads();

    int w = t >> 6, lane = t & 63;
    int lo = lane & 31, hi = lane >> 5;
    int px0 = blockIdx.x * 128 + w * 32;      // grid 1024

    bf16x8_t av[4];
    const unsigned short* hp = hbf + (size_t)(px0 + lo) * 64 + hi * 8;
#pragma unroll
    for (int ks = 0; ks < 4; ++ks)
        av[ks] = *(const bf16x8_t*)(hp + ks * 16);

    float res[16];
#pragma unroll
    for (int r = 0; r < 16; ++r) res[r] = 0.f;

#pragma unroll
    for (int jb = 0; jb < 4; ++jb) {
        f32x16_t acc = {};
        int j = jb * 32 + lo;
#pragma unroll
        for (int ks = 0; ks < 4; ++ks) {
            int byte = (j * 128 + ks * 32 + hi * 16) ^ ((j & 7) << 4);
            bf16x8_t bv = *(bf16x8_t*)((char*)Q + byte);
            acc = __builtin_amdgcn_mfma_f32_32x32x16_bf16(av[ks], bv, acc, 0, 0, 0);
        }
        float b1 = q1b[j];
        float w2 = q2[j];
#pragma unroll
        for (int r = 0; r < 16; ++r)
            res[r] = fmaf(fmaxf(acc[r] + b1, 0.f), w2, res[r]);
    }
#pragma unroll
    for (int r = 0; r < 16; ++r) {
        float v = res[r];
        v += __shfl_xor(v, 1);
        v += __shfl_xor(v, 2);
        v += __shfl_xor(v, 4);
        v += __shfl_xor(v, 8);
        v += __shfl_xor(v, 16);
        res[r] = v;
    }
    if (lo == 0) {
        float qb = q2b[0];
#pragma unroll
        for (int r = 0; r < 16; ++r) {
            int row = (r & 3) + 8 * (r >> 2) + 4 * hi;
            out[px0 + row] = res[r] + qb;
        }
    }
}

// ---------------- launch ----------------
extern "C" void kernel_launch(void* const* d_in, const int* in_sizes, int n_in,
                              void* d_out, int out_size, void* d_ws, size_t ws_size,
                              hipStream_t stream) {
    const float* x     = (const float*)d_in[0];
    const float* a     = (const float*)d_in[1];
    const float* pW    = (const float*)d_in[2];
    const float* pb    = (const float*)d_in[3];
    const float* q1W   = (const float*)d_in[4];
    const float* q1b   = (const float*)d_in[5];
    const float* q2W   = (const float*)d_in[6];
    const float* q2b   = (const float*)d_in[7];
    const float* phiW1 = (const float*)d_in[8];
    const float* phib1 = (const float*)d_in[9];
    const float* phiW2 = (const float*)d_in[10];
    const float* phib2 = (const float*)d_in[11];
    const float* phiW3 = (const float*)d_in[12];
    const float* phib3 = (const float*)d_in[13];
    const float* psiW1 = (const float*)d_in[14];
    const float* psib1 = (const float*)d_in[15];
    const float* psiW2 = (const float*)d_in[16];
    const float* psib2 = (const float*)d_in[17];
    const float* psiW3 = (const float*)d_in[18];
    const float* psib3 = (const float*)d_in[19];
    const float* lnG   = (const float*)d_in[20];
    const float* lnB   = (const float*)d_in[21];
    const float* convW = (const float*)d_in[22];
    const float* convb = (const float*)d_in[23];

    float* ws = (float*)d_ws;
    unsigned short* x1    = (unsigned short*)(ws + OFF_X1);
    unsigned short* yl1   = (unsigned short*)(ws + OFF_YL1);
    unsigned short* yl2   = (unsigned short*)(ws + OFF_YL2);
    unsigned short* hbf   = (unsigned short*)(ws + OFF_HBF);
    unsigned short* H2psi = (unsigned short*)(ws + OFF_H2PSI);
    unsigned short* x2c   = (unsigned short*)(ws + OFF_H2PSI);  // overlay: H2psi dead after k_gpart
    unsigned short* H2phi = (unsigned short*)(ws + OFF_H2PHI);
    unsigned short* cwtbf = (unsigned short*)(ws + OFF_CWTBF);
    unsigned short* q1bf  = (unsigned short*)(ws + OFF_Q1BF);
    unsigned short* w2t   = (unsigned short*)(ws + OFF_W2T);
    float* Gpart = ws + OFF_GPART;
    float* svpart= ws + OFF_SVP;
    float* G     = ws + OFF_G;
    float* sv    = ws + OFF_SV;
    float* C     = ws + OFF_C;
    float* D     = ws + OFF_D;

    k_setup<<<2528, 256, 0, stream>>>(convW, cwtbf, q1W, q1bf,
                                      psiW2, phiW2, w2t, x, a, pW, pb, hbf);

    for (int i = 0; i < 4; ++i) {
        k_convmlp<<<1696, 256, 0, stream>>>(hbf, cwtbf, convb, x1, yl1, yl2,
                                            a, x,
                                            psiW1 + i * 192, psib1 + i * 64, psib2 + i * 128,
                                            phiW1 + i * 192, phib1 + i * 64, phib2 + i * 128,
                                            w2t, H2psi, H2phi, i);
        k_gpart<<<512, 256, 0, stream>>>(hbf, H2psi, Gpart, svpart);
        k_gred<<<258, 256, 0, stream>>>(Gpart, svpart, G, sv);
        k_yc<<<32, 256, 0, stream>>>(G, sv,
                                     psiW3 + (size_t)i * 32768, psib3 + i * 256,
                                     phiW3 + (size_t)i * 32768, phib3 + i * 256,
                                     C, D);
        k_x2c<<<1024, 256, 0, stream>>>(H2phi, C, D, x2c);
        k_epilogue<<<8192, 256, 0, stream>>>(x1, yl1, yl2, x2c,
                                             lnG + i * 64, lnB + i * 64,
                                             hbf, (i < 3) ? 1 : 0);
    }

    k_head_mfma<<<1024, 256, 0, stream>>>(hbf, q1bf, q1b, q2W, q2b, (float*)d_out);
}

// Round 19
// 415.958 us; speedup vs baseline: 1.1277x; 1.0252x over previous
//
#include <hip/hip_runtime.h>
#include <cstddef>
#include <cstdint>

// ---------------- problem constants ----------------
// b=2, s=256, WIDTH=64, RANK=4, CLEVEL=1 (c=2), MLEVEL=2 (L=3), NB=4
// HID1=64, HID2=128

// ---------------- workspace layout (float-slot offsets) ----------------
// x1/yl1/yl2/x2c/H2psi/H2phi/h are bf16.
static constexpr size_t OFF_X1     = 0;          // bf16 2*256*256*64 -> 4194304 slots
static constexpr size_t OFF_YL1    = 4194304;    // bf16 -> 1048576
static constexpr size_t OFF_YL2    = 5242880;    // bf16 -> 262144
static constexpr size_t OFF_HBF    = 5505024;    // bf16 h -> 4194304
static constexpr size_t OFF_H2PSI  = 9699328;    // bf16 32768*128 -> 2097152 (x2c overlays)
static constexpr size_t OFF_H2PHI  = 11796480;   // 2097152
static constexpr size_t OFF_CWTBF  = 13893632;   // 221184
static constexpr size_t OFF_Q1BF   = 14114816;   // 4096
static constexpr size_t OFF_W2T    = 14118912;   // 8*8192 bf16 = 32768 float-slots
static constexpr size_t OFF_GPART  = 14151680;   // 512*8192 f32 = 4194304
static constexpr size_t OFF_SVP    = 18345984;   // 32768
static constexpr size_t OFF_G      = 18378752;   // 16384
static constexpr size_t OFF_SV     = 18395136;   // 128
static constexpr size_t OFF_C      = 18395264;   // 16384
static constexpr size_t OFF_D      = 18411648;   // 128
// end = 18411776 floats (~73.6 MB) <= proven-available 134.3 MB

typedef __attribute__((ext_vector_type(8)))  short bf16x8_t;   // 8 bf16 in 4 VGPRs
typedef __attribute__((ext_vector_type(16))) float f32x16_t;   // 32x32 MFMA acc

// ---------------- helpers ----------------
__device__ inline float wave_sum64(float v) {
    v += __shfl_xor(v, 1);
    v += __shfl_xor(v, 2);
    v += __shfl_xor(v, 4);
    v += __shfl_xor(v, 8);
    v += __shfl_xor(v, 16);
    v += __shfl_xor(v, 32);
    return v;
}

__device__ inline unsigned short f2bf(float f) {   // round-to-nearest-even
    uint32_t u = __float_as_uint(f);
    uint32_t r = u + 0x7FFFu + ((u >> 16) & 1u);
    return (unsigned short)(r >> 16);
}
__device__ inline float bf2f(unsigned short u) {
    return __uint_as_float((uint32_t)u << 16);
}
// 8 bf16 (uint4) -> 8 f32
__device__ inline void bf8_to_f(uint4 u, float* d) {
    unsigned uv[4] = {u.x, u.y, u.z, u.w};
#pragma unroll
    for (int i = 0; i < 4; ++i) {
        d[2 * i]     = __uint_as_float((uv[i] & 0xFFFFu) << 16);
        d[2 * i + 1] = __uint_as_float(uv[i] & 0xFFFF0000u);
    }
}

// full-res flat pixel index of coarse pixel (b, n): n in [0,16384)
__device__ inline size_t fullpix(int b, int n) {
    return (size_t)(b * 65536 + (n >> 7) * 512 + ((n & 127) << 1));
}

struct Lerp { int i0, i1; float f; };
__device__ inline Lerp lcoord(int o, float r, float off, int Sin) {
    float s = fmaxf(fmaf((float)o, r, off), 0.f);
    Lerp L;
    L.i0 = (int)s;
    L.f  = s - (float)L.i0;
    L.i1 = min(L.i0 + 1, Sin - 1);
    return L;
}

// ---------------- fused setup: convW | q1 | W2 frag-order | lift ----------------
// grid 2528: [0,1728) convW; [1728,1760) q1; [1760,2016) W2t; [2016,2528) lift
__global__ __launch_bounds__(256) void k_setup(const float* __restrict__ convW,
                                               unsigned short* __restrict__ cwt,
                                               const float* __restrict__ q1W,
                                               unsigned short* __restrict__ q1bf,
                                               const float* __restrict__ psiW2,
                                               const float* __restrict__ phiW2,
                                               unsigned short* __restrict__ w2t,
                                               const float* __restrict__ x,
                                               const float* __restrict__ a,
                                               const float* __restrict__ pW,
                                               const float* __restrict__ pb,
                                               unsigned short* __restrict__ hbf) {
    int bid = blockIdx.x;
    int t = threadIdx.x;
    if (bid < 1728) {
        // convW[i][l][oc][ic][3][3] f32 -> wt[((il*9+tap)*4+kq)*1024 + hi*512 + oc*8 + j]
        int idx = bid * 256 + t;                  // 442368
        if (idx >= 442368) return;
        int j    = idx & 7;
        int oc   = (idx >> 3) & 63;
        int hi   = (idx >> 9) & 1;
        int kq   = (idx >> 10) & 3;
        int rest = idx >> 12;                     // il*9 + tap
        int tap  = rest % 9;
        int il   = rest / 9;
        int ic   = kq * 16 + hi * 8 + j;
        cwt[idx] = f2bf(convW[((size_t)(il * 64 + oc) * 64 + ic) * 9 + tap]);
    } else if (bid < 1760) {
        int idx = (bid - 1728) * 256 + t;         // 8192
        int k = idx & 63;
        int j = idx >> 6;
        q1bf[j * 64 + k] = f2bf(q1W[k * 128 + j]);
    } else if (bid < 2016) {
        // W2[m][i][64 k][128 j] -> w2t[((((m*4+i)*4+jt)*4+kq)*2+hi)*256 + lo*8 + jj]
        int idx = (bid - 1760) * 256 + t;         // 65536
        int jj = idx & 7;
        int lo = (idx >> 3) & 31;
        int hi = (idx >> 8) & 1;
        int kq = (idx >> 9) & 3;
        int jt = (idx >> 11) & 3;
        int i  = (idx >> 13) & 3;
        int m  = idx >> 15;
        int k  = kq * 16 + hi * 8 + jj;
        int j  = jt * 32 + lo;
        const float* W2 = m ? phiW2 : psiW2;
        w2t[idx] = f2bf(W2[(size_t)i * 8192 + k * 128 + j]);
    } else {
        int p = (bid - 2016) * 256 + t;           // 131072
        float a0 = a[(size_t)p * 2 + 0];
        float a1 = a[(size_t)p * 2 + 1];
        float xv = x[p];
        float vals[64];
#pragma unroll
        for (int c = 0; c < 64; ++c)
            vals[c] = fmaf(a0, pW[c], fmaf(a1, pW[64 + c], fmaf(xv, pW[128 + c], pb[c])));
        unsigned short us[64];
#pragma unroll
        for (int c = 0; c < 64; ++c) us[c] = f2bf(vals[c]);
        unsigned short* bp = hbf + (size_t)p * 64;
#pragma unroll
        for (int c = 0; c < 64; c += 8)
            *(uint4*)(bp + c) = *(uint4*)(us + c);
    }
}

// ---------------- fused conv (blocks 0..1343) + mlp-MFMA (blocks 1344..2367) ----------------
// conv: 16x8 px tile, A-only LDS 23 KB (halo 10x18x64 bf16) -> ~6 blocks/CU,
//       frag-order B from L2 (reg dbuf), direct bf16 stores. Wave = 32 px x 64 oc.
// mlp:  h1 per-lane + W2-GEMM via MFMA; outputs bf16.
__global__ __launch_bounds__(256) void k_convmlp(
    const unsigned short* __restrict__ hbf,   // [2][256][256][64] bf16
    const unsigned short* __restrict__ wbf,   // conv W frag-order, 36864 per (iter,lvl)
    const float* __restrict__ convb,          // [12][64]
    unsigned short* __restrict__ x1, unsigned short* __restrict__ yl1,
    unsigned short* __restrict__ yl2,
    const float* __restrict__ a, const float* __restrict__ x,
    const float* __restrict__ W1a, const float* __restrict__ b1a,
    const float* __restrict__ b2a,
    const float* __restrict__ W1b, const float* __restrict__ b1b,
    const float* __restrict__ b2b,
    const unsigned short* __restrict__ w2t,   // mlp W2 frag-order
    unsigned short* __restrict__ H2a, unsigned short* __restrict__ H2b,
    int iter) {
    __shared__ unsigned short Ald[11520];     // 180 halo px * 64 ic (23040 B)
    int bid = blockIdx.x;
    int t = threadIdx.x;

    if (bid >= 1344) {
        // ---------------- mlp path (MFMA) ----------------
        int blk = bid - 1344;                      // 0..1023
        int m = blk >> 9;                          // 0=psi, 1=phi
        int px0 = (blk & 511) << 6;                // 64 px per block
        const float* W1 = m ? W1b : W1a;
        const float* b1 = m ? b1b : b1a;
        const float* b2 = m ? b2b : b2a;
        unsigned short* H2 = m ? H2b : H2a;

        int w    = t >> 6;                         // j-tile 0..3
        int lane = t & 63;
        int lo   = lane & 31;
        int hi   = lane >> 5;

        int pxlA = px0 + lo, pxlB = px0 + 32 + lo;
        int bA = pxlA >> 14;
        size_t apA = fullpix(bA, pxlA & 16383);
        size_t apB = fullpix(bA, pxlB & 16383);
        float a0A = a[apA * 2], a1A = a[apA * 2 + 1], xvA = x[apA];
        float a0B = a[apB * 2], a1B = a[apB * 2 + 1], xvB = x[apB];

        bf16x8_t faA[4], faB[4];
#pragma unroll
        for (int kq = 0; kq < 4; ++kq) {
            unsigned short tA[8], tB[8];
#pragma unroll
            for (int jj = 0; jj < 8; ++jj) {
                int k = kq * 16 + hi * 8 + jj;
                float w1a = W1[k], w1b = W1[64 + k], w1c = W1[128 + k], bb = b1[k];
                tA[jj] = f2bf(fmaxf(fmaf(a0A, w1a, fmaf(a1A, w1b, fmaf(xvA, w1c, bb))), 0.f));
                tB[jj] = f2bf(fmaxf(fmaf(a0B, w1a, fmaf(a1B, w1b, fmaf(xvB, w1c, bb))), 0.f));
            }
            faA[kq] = *(bf16x8_t*)tA;
            faB[kq] = *(bf16x8_t*)tB;
        }
        const unsigned short* wb =
            w2t + (size_t)(((m * 4 + iter) * 4 + w) * 4) * 512 + hi * 256 + lo * 8;
        f32x16_t accA = {}, accB = {};
#pragma unroll
        for (int kq = 0; kq < 4; ++kq) {
            bf16x8_t fb = *(const bf16x8_t*)(wb + kq * 512);
            accA = __builtin_amdgcn_mfma_f32_32x32x16_bf16(faA[kq], fb, accA, 0, 0, 0);
            accB = __builtin_amdgcn_mfma_f32_32x32x16_bf16(faB[kq], fb, accB, 0, 0, 0);
        }
        float bias2 = b2[w * 32 + lo];
#pragma unroll
        for (int reg = 0; reg < 16; ++reg) {
            int row = (reg & 3) + 8 * (reg >> 2) + 4 * hi;
            H2[(size_t)(px0 + row) * 128 + w * 32 + lo]      = f2bf(fmaxf(accA[reg] + bias2, 0.f));
            H2[(size_t)(px0 + 32 + row) * 128 + w * 32 + lo] = f2bf(fmaxf(accB[reg] + bias2, 0.f));
        }
        return;
    }

    // ---------------- conv path (16 wide x 8 tall tile) ----------------
    int lvl, tix, Sl, st, tpb, tprx;
    if (bid < 1024)      { lvl = 0; tix = bid;        Sl = 256; st = 1; tpb = 512; tprx = 16; }
    else if (bid < 1280) { lvl = 1; tix = bid - 1024; Sl = 128; st = 2; tpb = 128; tprx = 8;  }
    else                 { lvl = 2; tix = bid - 1280; Sl = 64;  st = 4; tpb = 32;  tprx = 4;  }
    int b = tix / tpb;
    int r = tix - b * tpb;
    int y0 = (r / tprx) << 3, x0 = (r % tprx) << 4;

    // ---- stage A: 10x18 halo x 64 ic, zero-padded ----
    for (int c = t; c < 1440; c += 256) {       // 180 rows * 8 slots(16B)
        int lin = c >> 3, slot = c & 7;
        int ty = lin / 18, tx = lin - ty * 18;
        int oy = y0 + ty - 1, ox = x0 + tx - 1;
        uint4 val = make_uint4(0u, 0u, 0u, 0u);
        if ((unsigned)oy < (unsigned)Sl && (unsigned)ox < (unsigned)Sl) {
            const unsigned short* src =
                hbf + (((size_t)(b * 256 + oy * st) * 256 + ox * st) << 6) + (slot << 3);
            val = *(const uint4*)src;
        }
        int byte = (lin << 7) + (((slot ^ (lin & 7))) << 4);
        *(uint4*)((char*)Ald + byte) = val;
    }
    __syncthreads();

    int w    = t >> 6;                          // wave: rows 2w..2w+1 (32 px)
    int lane = t & 63;
    int lo   = lane & 31;
    int hi   = lane >> 5;
    f32x16_t acc00 = {}, acc01 = {};

    const unsigned short* wbase =
        wbf + (size_t)(iter * 3 + lvl) * 36864 + hi * 512 + lo * 8;

    int yA0 = 2 * w + (lo >> 4);
    int xA  = lo & 15;

    bf16x8_t v0c[4], v1c[4], v0n[4], v1n[4];
#pragma unroll
    for (int kq = 0; kq < 4; ++kq) {
        v0c[kq] = *(const bf16x8_t*)(wbase + kq * 1024);
        v1c[kq] = *(const bf16x8_t*)(wbase + kq * 1024 + 256);
    }
#pragma unroll
    for (int tap = 0; tap < 9; ++tap) {
        if (tap < 8) {
#pragma unroll
            for (int kq = 0; kq < 4; ++kq) {
                int keo = ((tap + 1) * 4 + kq) * 1024;
                v0n[kq] = *(const bf16x8_t*)(wbase + keo);
                v1n[kq] = *(const bf16x8_t*)(wbase + keo + 256);
            }
        }
        int dy = tap / 3, dx = tap - dy * 3;
        int lin0 = (yA0 + dy) * 18 + (xA + dx);
#pragma unroll
        for (int kq = 0; kq < 4; ++kq) {
            int icb = (kq << 5) + (hi << 4);            // byte offset in A row
            int a0b = ((lin0 << 7) + icb) ^ ((lin0 & 7) << 4);
            bf16x8_t va0 = *(bf16x8_t*)((char*)Ald + a0b);
            acc00 = __builtin_amdgcn_mfma_f32_32x32x16_bf16(va0, v0c[kq], acc00, 0, 0, 0);
            acc01 = __builtin_amdgcn_mfma_f32_32x32x16_bf16(va0, v1c[kq], acc01, 0, 0, 0);
        }
#pragma unroll
        for (int kq = 0; kq < 4; ++kq) { v0c[kq] = v0n[kq]; v1c[kq] = v1n[kq]; }
    }

    // ---- store bf16 (C layout: col=lo -> oc, row=(reg&3)+8*(reg>>2)+4*hi -> px) ----
    unsigned short* out = (lvl == 0) ? x1 : (lvl == 1 ? yl1 : yl2);
    const float* bias = convb + (iter * 3 + lvl) * 64;
    float bias0 = bias[lo];
    float bias1 = bias[32 + lo];
#pragma unroll
    for (int reg = 0; reg < 16; ++reg) {
        int row = (reg & 3) + 8 * (reg >> 2) + 4 * hi;   // 0..31
        int yt  = 2 * w + (row >> 4);
        int xt  = row & 15;
        size_t pix = ((size_t)(b * Sl + y0 + yt) * Sl + (x0 + xt)) << 6;
        out[pix + lo]      = f2bf(acc00[reg] + bias0);
        out[pix + 32 + lo] = f2bf(acc01[reg] + bias1);
    }
}

// ---------------- split-K stage 1: Gpart[blk] = v^T H2psi over 64 px; svpart ----------------
__global__ __launch_bounds__(256) void k_gpart(const unsigned short* __restrict__ hbf,
                                               const unsigned short* __restrict__ H2psi,
                                               float* __restrict__ Gpart,
                                               float* __restrict__ svpart) {
    __shared__ float vt[4096];       // [64 px][64 w]
    __shared__ float h2t[8192];      // [64 px][128 j]
    int blk = blockIdx.x;            // 512
    int b = blk >> 8;
    int n0 = (blk & 255) << 6;
    int t = threadIdx.x;
    int pxq = t >> 2, qq = t & 3;
    int sw = (pxq & 7) << 4;
    {
        const unsigned short* src = hbf + fullpix(b, n0 + pxq) * 64 + qq * 16;
        uint4 u0 = *(const uint4*)src;
        uint4 u1 = *(const uint4*)(src + 8);
        float f[16];
        bf8_to_f(u0, f);
        bf8_to_f(u1, f + 8);
#pragma unroll
        for (int j = 0; j < 4; ++j) {
            int byte = (pxq * 256 + qq * 64 + j * 16) ^ sw;
            *(float4*)((char*)vt + byte) = make_float4(f[4 * j], f[4 * j + 1],
                                                       f[4 * j + 2], f[4 * j + 3]);
        }
        const unsigned short* hsrc = H2psi + ((size_t)(b * 16384 + n0 + pxq)) * 128 + qq * 32;
#pragma unroll
        for (int rr = 0; rr < 4; ++rr) {
            uint4 hu = *(const uint4*)(hsrc + rr * 8);
            float g[8];
            bf8_to_f(hu, g);
            int byte0 = (pxq * 512 + qq * 128 + rr * 32) ^ sw;
            int byte1 = (pxq * 512 + qq * 128 + rr * 32 + 16) ^ sw;
            *(float4*)((char*)h2t + byte0) = make_float4(g[0], g[1], g[2], g[3]);
            *(float4*)((char*)h2t + byte1) = make_float4(g[4], g[5], g[6], g[7]);
        }
    }
    __syncthreads();

    int wt_ = (t >> 5) << 3;         // 0..56
    int kt  = (t & 31) << 2;         // 0..124
    float acc[8][4];
#pragma unroll
    for (int i = 0; i < 8; ++i)
#pragma unroll
        for (int j = 0; j < 4; ++j) acc[i][j] = 0.f;

#pragma unroll 4
    for (int nn = 0; nn < 64; ++nn) {
        int nsw = (nn & 7) << 4;
        float4 hv = *(float4*)((char*)h2t + ((nn * 512 + kt * 4) ^ nsw));
        float4 v0 = *(float4*)((char*)vt + ((nn * 256 + wt_ * 4) ^ nsw));
        float4 v1 = *(float4*)((char*)vt + ((nn * 256 + wt_ * 4 + 16) ^ nsw));
        float vv[8] = {v0.x, v0.y, v0.z, v0.w, v1.x, v1.y, v1.z, v1.w};
        float hh[4] = {hv.x, hv.y, hv.z, hv.w};
#pragma unroll
        for (int i = 0; i < 8; ++i)
#pragma unroll
            for (int j = 0; j < 4; ++j) acc[i][j] = fmaf(vv[i], hh[j], acc[i][j]);
    }

    float* gp = Gpart + (size_t)blk * 8192;
#pragma unroll
    for (int i = 0; i < 8; ++i)
        *(float4*)&gp[(wt_ + i) * 128 + kt] =
            make_float4(acc[i][0], acc[i][1], acc[i][2], acc[i][3]);

    if (t < 64) {
        float s = 0.f;
#pragma unroll 8
        for (int p = 0; p < 64; ++p)
            s += *(float*)((char*)vt + ((p * 256 + t * 4) ^ ((p & 7) << 4)));
        svpart[blk * 64 + t] = s;
    }
}

// ---------------- reduce: G = sum Gpart; sv = sum svpart (grid 258) ----------------
__global__ __launch_bounds__(256) void k_gred(const float* __restrict__ Gpart,
                                              const float* __restrict__ svpart,
                                              float* __restrict__ G,
                                              float* __restrict__ sv) {
    __shared__ float red[4][64];
    int blk = blockIdx.x;
    int t = threadIdx.x;
    if (blk < 256) {
        int b  = blk >> 7;
        int es = (blk & 127) << 6;
        int e  = es + (t & 63);
        int cg = t >> 6;
        float s = 0.f;
        const float* gp = Gpart + ((size_t)(b * 256 + cg * 64)) * 8192 + e;
#pragma unroll 8
        for (int c = 0; c < 64; ++c) s += gp[(size_t)c * 8192];
        red[cg][t & 63] = s;
        __syncthreads();
        if (t < 64)
            G[b * 8192 + es + t] = red[0][t] + red[1][t] + red[2][t] + red[3][t];
    } else {
        int b = blk - 256;
        int w = t & 63, cg = t >> 6;
        float s = 0.f;
        const float* sp = svpart + ((size_t)(b * 256 + cg * 64)) * 64 + w;
#pragma unroll 8
        for (int c = 0; c < 64; ++c) s += sp[c * 64];
        red[cg][w] = s;
        __syncthreads();
        if (t < 64) sv[b * 64 + t] = red[0][t] + red[1][t] + red[2][t] + red[3][t];
    }
}

// ---------------- yc: ybar -> C[b][w][k], D[b][w] (grid 32) ----------------
__global__ __launch_bounds__(256) void k_yc(const float* __restrict__ G,
                                            const float* __restrict__ sv,
                                            const float* __restrict__ W3psi,
                                            const float* __restrict__ b3psi,
                                            const float* __restrict__ W3phi,
                                            const float* __restrict__ b3phi,
                                            float* __restrict__ C,
                                            float* __restrict__ D) {
    __shared__ float ybar[256];
    int bq = blockIdx.x;             // 32
    int b = bq >> 4, q = bq & 15;
    int t = threadIdx.x;
    {
        int o = t, w = o >> 2;
        const float* gp = &G[(size_t)(b * 64 + w) * 128];
        float s0 = 0.f, s1 = 0.f, s2 = 0.f, s3 = 0.f;
#pragma unroll 4
        for (int k = 0; k < 128; k += 4) {
            s0 = fmaf(W3psi[(k + 0) * 256 + o], gp[k + 0], s0);
            s1 = fmaf(W3psi[(k + 1) * 256 + o], gp[k + 1], s1);
            s2 = fmaf(W3psi[(k + 2) * 256 + o], gp[k + 2], s2);
            s3 = fmaf(W3psi[(k + 3) * 256 + o], gp[k + 3], s3);
        }
        float s = b3psi[o] * sv[b * 64 + w] + ((s0 + s1) + (s2 + s3));
        ybar[o] = s * (1.f / 16384.f);
    }
    __syncthreads();
#pragma unroll
    for (int rep = 0; rep < 2; ++rep) {
        int e = q * 512 + rep * 256 + t;   // slice of 8192
        int w = e >> 7, k = e & 127;
        const float* wp = &W3phi[k * 256 + w * 4];
        C[b * 8192 + e] = fmaf(wp[0], ybar[w * 4],
                          fmaf(wp[1], ybar[w * 4 + 1],
                          fmaf(wp[2], ybar[w * 4 + 2], wp[3] * ybar[w * 4 + 3])));
    }
    if (q == 0 && t < 64) {
        int w = t;
        D[b * 64 + w] = b3phi[w * 4] * ybar[w * 4] + b3phi[w * 4 + 1] * ybar[w * 4 + 1]
                      + b3phi[w * 4 + 2] * ybar[w * 4 + 2] + b3phi[w * 4 + 3] * ybar[w * 4 + 3];
    }
}

// ---------------- x2c: x2c[px][w] = H2phi[px][:].C[b][w][:] + D[b][w] (grid 1024) ----------------
__global__ __launch_bounds__(256) void k_x2c(const unsigned short* __restrict__ H2phi,
                                             const float* __restrict__ C,
                                             const float* __restrict__ D,
                                             unsigned short* __restrict__ x2c) {
    __shared__ float cl[8192];       // C[b]: [64 w][128 k] (32 KB)
    __shared__ float h2l[4096];      // [32 px][128 k], XOR-swizzled (16 KB)
    __shared__ float Dl[64];
    int blk = blockIdx.x;            // 1024: 512 per b
    int b = blk >> 9;
    int px0 = (blk & 511) << 5;      // 32 px per block
    int t = threadIdx.x;

    const float* cp = C + b * 8192;
#pragma unroll
    for (int r = 0; r < 8; ++r) {
        int f = r * 1024 + t * 4;
        *(float4*)&cl[f] = *(const float4*)&cp[f];
    }
    if (t < 64) Dl[t] = D[b * 64 + t];
    {   // stage H2phi tile (bf16 -> f32), swizzled
        const unsigned short* hsrc = H2phi + ((size_t)(b * 16384 + px0)) * 128;
#pragma unroll
        for (int r = 0; r < 2; ++r) {
            int f = r * 2048 + t * 8;              // float index, 8 per rep
            uint4 u = *(const uint4*)(hsrc + f);
            float d[8];
            bf8_to_f(u, d);
            int px = f >> 7;
            int sw2 = ((px & 7) << 4) ^ (((px >> 3) & 1) << 6);
            *(float4*)((char*)h2l + ((f * 4) ^ sw2))      = make_float4(d[0], d[1], d[2], d[3]);
            *(float4*)((char*)h2l + ((f * 4 + 16) ^ sw2)) = make_float4(d[4], d[5], d[6], d[7]);
        }
    }
    __syncthreads();

    int px = t & 31;
    int w0 = (t >> 5) << 3;          // 0..56: 8 w per thread
    int psw = ((px & 7) << 4) ^ (((px >> 3) & 1) << 6);
    float acc[8];
#pragma unroll
    for (int j = 0; j < 8; ++j) acc[j] = 0.f;

#pragma unroll 4
    for (int kq = 0; kq < 32; ++kq) {
        float4 hq = *(float4*)((char*)h2l + ((px * 512 + kq * 16) ^ psw));
#pragma unroll
        for (int j = 0; j < 8; ++j) {
            float4 cq = *(float4*)&cl[(w0 + j) * 128 + kq * 4];
            acc[j] = fmaf(hq.x, cq.x, acc[j]);
            acc[j] = fmaf(hq.y, cq.y, acc[j]);
            acc[j] = fmaf(hq.z, cq.z, acc[j]);
            acc[j] = fmaf(hq.w, cq.w, acc[j]);
        }
    }
    unsigned short us[8];
#pragma unroll
    for (int j = 0; j < 8; ++j) us[j] = f2bf(acc[j] + Dl[w0 + j]);
    unsigned short* op = x2c + ((size_t)(b * 16384 + px0 + px)) * 64 + w0;
    *(uint4*)op = *(uint4*)us;
}

// ---------------- epilogue: h = LN(x1 + up(yl1) + up(yl2) + up(x2c)); bf16 in/out ----------------
__global__ __launch_bounds__(256) void k_epilogue(const unsigned short* __restrict__ x1,
                                                  const unsigned short* __restrict__ yl1,
                                                  const unsigned short* __restrict__ yl2,
                                                  const unsigned short* __restrict__ x2c,
                                                  const float* __restrict__ lnG,
                                                  const float* __restrict__ lnB,
                                                  unsigned short* __restrict__ hbf,
                                                  int do_relu) {
    __shared__ float y1s[2][10][64];   // yl1 corners (scale 2)
    __shared__ float xcs[2][10][64];   // x2c corners (scale 2)
    __shared__ float y2s[2][6][64];    // yl2 corners (scale 4)
    int t    = threadIdx.x;
    int blk  = blockIdx.x;                 // 8192 = 2 * 256 * 16
    int b    = blk >> 12;
    int rest = blk & 4095;
    int y    = rest >> 4;
    int x0   = (rest & 15) << 4;
    int wv = t >> 6, lane = t & 63;

    Lerp ly1 = lcoord(y, 0.5f, -0.25f, 128);    // yl1 & x2c
    Lerp ly2 = lcoord(y, 0.25f, -0.375f, 64);   // yl2
    int c1 = max(0, (int)floorf((float)x0 * 0.5f - 0.25f));
    int c2 = max(0, (int)floorf((float)x0 * 0.25f - 0.375f));

    const unsigned short* Y1 = yl1 + (size_t)b * 16384 * 64;
    const unsigned short* Y2 = yl2 + (size_t)b * 4096 * 64;
    const unsigned short* XC = x2c + (size_t)b * 16384 * 64;
    for (int f4 = t; f4 < 832; f4 += 256) {
        int e, row, col;
        const unsigned short* src;
        float* dst;
        if (f4 < 320) {                 // y1s
            e = f4 * 4;
            int r = e / 640, rm = e - r * 640;
            int j = rm >> 6, ch = rm & 63;
            row = r ? ly1.i1 : ly1.i0;
            col = min(c1 + j, 127);
            src = &Y1[((size_t)(row * 128 + col)) * 64 + ch];
            dst = &y1s[r][j][ch];
        } else if (f4 < 640) {          // xcs
            e = (f4 - 320) * 4;
            int r = e / 640, rm = e - r * 640;
            int j = rm >> 6, ch = rm & 63;
            row = r ? ly1.i1 : ly1.i0;
            col = min(c1 + j, 127);
            src = &XC[((size_t)(row * 128 + col)) * 64 + ch];
            dst = &xcs[r][j][ch];
        } else {                        // y2s
            e = (f4 - 640) * 4;
            int r = e / 384, rm = e - r * 384;
            int j = rm >> 6, ch = rm & 63;
            row = r ? ly2.i1 : ly2.i0;
            col = min(c2 + j, 63);
            src = &Y2[((size_t)(row * 64 + col)) * 64 + ch];
            dst = &y2s[r][j][ch];
        }
        uint2 u = *(const uint2*)src;   // 4 bf16
        dst[0] = __uint_as_float((u.x & 0xFFFFu) << 16);
        dst[1] = __uint_as_float(u.x & 0xFFFF0000u);
        dst[2] = __uint_as_float((u.y & 0xFFFFu) << 16);
        dst[3] = __uint_as_float(u.y & 0xFFFF0000u);
    }
    __syncthreads();

    float g = lnG[lane], be = lnB[lane];
    for (int pp = 0; pp < 4; ++pp) {
        int xx = x0 + wv * 4 + pp;
        size_t pix = (size_t)((b * 256 + y) * 256 + xx);
        float v = bf2f(x1[pix * 64 + lane]);
        {   // yl1 + x2c (shared x-lerp)
            Lerp lx = lcoord(xx, 0.5f, -0.25f, 128);
            int j0 = lx.i0 - c1, j1 = lx.i1 - c1;
            float a0 = y1s[0][j0][lane], a1 = y1s[0][j1][lane];
            float b0 = y1s[1][j0][lane], b1 = y1s[1][j1][lane];
            float ta = a0 + lx.f * (a1 - a0);
            float tb = b0 + lx.f * (b1 - b0);
            v += ta + ly1.f * (tb - ta);
            float p0 = xcs[0][j0][lane], p1 = xcs[0][j1][lane];
            float q0 = xcs[1][j0][lane], q1 = xcs[1][j1][lane];
            float tp = p0 + lx.f * (p1 - p0);
            float tq = q0 + lx.f * (q1 - q0);
            v += tp + ly1.f * (tq - tp);
        }
        {   // yl2
            Lerp lx = lcoord(xx, 0.25f, -0.375f, 64);
            int j0 = lx.i0 - c2, j1 = lx.i1 - c2;
            float a0 = y2s[0][j0][lane], a1 = y2s[0][j1][lane];
            float b0 = y2s[1][j0][lane], b1 = y2s[1][j1][lane];
            float ta = a0 + lx.f * (a1 - a0);
            float tb = b0 + lx.f * (b1 - b0);
            v += ta + ly2.f * (tb - ta);
        }
        float mu  = wave_sum64(v) * (1.f / 64.f);
        float d   = v - mu;
        float var = wave_sum64(d * d) * (1.f / 64.f);
        float ov  = fmaf(d * rsqrtf(var + 1e-5f), g, be);
        if (do_relu) ov = fmaxf(ov, 0.f);
        hbf[pix * 64 + lane] = f2bf(ov);
    }
}

// ---------------- head (MFMA): out = relu(hbf@q1W+q1b) . q2 + q2b ----------------
__global__ __launch_bounds__(256) void k_head_mfma(
    const unsigned short* __restrict__ hbf,   // [131072][64] bf16
    const unsigned short* __restrict__ q1bf,  // [128 j][64 k] bf16
    const float* __restrict__ q1b,            // [128]
    const float* __restrict__ q2,             // [128]
    const float* __restrict__ q2b,            // [1]
    float* __restrict__ out) {
    __shared__ unsigned short Q[8192];        // [j][k] swizzled
    int t = threadIdx.x;
    for (int c = t; c < 1024; c += 256) {
        int j = c >> 3, slot = c & 7;
        uint4 v = *(const uint4*)(q1bf + j * 64 + slot * 8);
        int byte = (j * 128 + slot * 16) ^ ((j & 7) << 4);
        *(uint4*)((char*)Q + byte) = v;
    }
    __syncthreads();

    int w = t >> 6, lane = t & 63;
    int lo = lane & 31, hi = lane >> 5;
    int px0 = blockIdx.x * 128 + w * 32;      // grid 1024

    bf16x8_t av[4];
    const unsigned short* hp = hbf + (size_t)(px0 + lo) * 64 + hi * 8;
#pragma unroll
    for (int ks = 0; ks < 4; ++ks)
        av[ks] = *(const bf16x8_t*)(hp + ks * 16);

    float res[16];
#pragma unroll
    for (int r = 0; r < 16; ++r) res[r] = 0.f;

#pragma unroll
    for (int jb = 0; jb < 4; ++jb) {
        f32x16_t acc = {};
        int j = jb * 32 + lo;
#pragma unroll
        for (int ks = 0; ks < 4; ++ks) {
            int byte = (j * 128 + ks * 32 + hi * 16) ^ ((j & 7) << 4);
            bf16x8_t bv = *(bf16x8_t*)((char*)Q + byte);
            acc = __builtin_amdgcn_mfma_f32_32x32x16_bf16(av[ks], bv, acc, 0, 0, 0);
        }
        float b1 = q1b[j];
        float w2 = q2[j];
#pragma unroll
        for (int r = 0; r < 16; ++r)
            res[r] = fmaf(fmaxf(acc[r] + b1, 0.f), w2, res[r]);
    }
#pragma unroll
    for (int r = 0; r < 16; ++r) {
        float v = res[r];
        v += __shfl_xor(v, 1);
        v += __shfl_xor(v, 2);
        v += __shfl_xor(v, 4);
        v += __shfl_xor(v, 8);
        v += __shfl_xor(v, 16);
        res[r] = v;
    }
    if (lo == 0) {
        float qb = q2b[0];
#pragma unroll
        for (int r = 0; r < 16; ++r) {
            int row = (r & 3) + 8 * (r >> 2) + 4 * hi;
            out[px0 + row] = res[r] + qb;
        }
    }
}

// ---------------- launch ----------------
extern "C" void kernel_launch(void* const* d_in, const int* in_sizes, int n_in,
                              void* d_out, int out_size, void* d_ws, size_t ws_size,
                              hipStream_t stream) {
    const float* x     = (const float*)d_in[0];
    const float* a     = (const float*)d_in[1];
    const float* pW    = (const float*)d_in[2];
    const float* pb    = (const float*)d_in[3];
    const float* q1W   = (const float*)d_in[4];
    const float* q1b   = (const float*)d_in[5];
    const float* q2W   = (const float*)d_in[6];
    const float* q2b   = (const float*)d_in[7];
    const float* phiW1 = (const float*)d_in[8];
    const float* phib1 = (const float*)d_in[9];
    const float* phiW2 = (const float*)d_in[10];
    const float* phib2 = (const float*)d_in[11];
    const float* phiW3 = (const float*)d_in[12];
    const float* phib3 = (const float*)d_in[13];
    const float* psiW1 = (const float*)d_in[14];
    const float* psib1 = (const float*)d_in[15];
    const float* psiW2 = (const float*)d_in[16];
    const float* psib2 = (const float*)d_in[17];
    const float* psiW3 = (const float*)d_in[18];
    const float* psib3 = (const float*)d_in[19];
    const float* lnG   = (const float*)d_in[20];
    const float* lnB   = (const float*)d_in[21];
    const float* convW = (const float*)d_in[22];
    const float* convb = (const float*)d_in[23];

    float* ws = (float*)d_ws;
    unsigned short* x1    = (unsigned short*)(ws + OFF_X1);
    unsigned short* yl1   = (unsigned short*)(ws + OFF_YL1);
    unsigned short* yl2   = (unsigned short*)(ws + OFF_YL2);
    unsigned short* hbf   = (unsigned short*)(ws + OFF_HBF);
    unsigned short* H2psi = (unsigned short*)(ws + OFF_H2PSI);
    unsigned short* x2c   = (unsigned short*)(ws + OFF_H2PSI);  // overlay: H2psi dead after k_gpart
    unsigned short* H2phi = (unsigned short*)(ws + OFF_H2PHI);
    unsigned short* cwtbf = (unsigned short*)(ws + OFF_CWTBF);
    unsigned short* q1bf  = (unsigned short*)(ws + OFF_Q1BF);
    unsigned short* w2t   = (unsigned short*)(ws + OFF_W2T);
    float* Gpart = ws + OFF_GPART;
    float* svpart= ws + OFF_SVP;
    float* G     = ws + OFF_G;
    float* sv    = ws + OFF_SV;
    float* C     = ws + OFF_C;
    float* D     = ws + OFF_D;

    k_setup<<<2528, 256, 0, stream>>>(convW, cwtbf, q1W, q1bf,
                                      psiW2, phiW2, w2t, x, a, pW, pb, hbf);

    for (int i = 0; i < 4; ++i) {
        k_convmlp<<<2368, 256, 0, stream>>>(hbf, cwtbf, convb, x1, yl1, yl2,
                                            a, x,
                                            psiW1 + i * 192, psib1 + i * 64, psib2 + i * 128,
                                            phiW1 + i * 192, phib1 + i * 64, phib2 + i * 128,
                                            w2t, H2psi, H2phi, i);
        k_gpart<<<512, 256, 0, stream>>>(hbf, H2psi, Gpart, svpart);
        k_gred<<<258, 256, 0, stream>>>(Gpart, svpart, G, sv);
        k_yc<<<32, 256, 0, stream>>>(G, sv,
                                     psiW3 + (size_t)i * 32768, psib3 + i * 256,
                                     phiW3 + (size_t)i * 32768, phib3 + i * 256,
                                     C, D);
        k_x2c<<<1024, 256, 0, stream>>>(H2phi, C, D, x2c);
        k_epilogue<<<8192, 256, 0, stream>>>(x1, yl1, yl2, x2c,
                                             lnG + i * 64, lnB + i * 64,
                                             hbf, (i < 3) ? 1 : 0);
    }

    k_head_mfma<<<1024, 256, 0, stream>>>(hbf, q1bf, q1b, q2W, q2b, (float*)d_out);
}

// Round 20
// 407.590 us; speedup vs baseline: 1.1509x; 1.0205x over previous
//
#include <hip/hip_runtime.h>
#include <cstddef>
#include <cstdint>

// ---------------- problem constants ----------------
// b=2, s=256, WIDTH=64, RANK=4, CLEVEL=1 (c=2), MLEVEL=2 (L=3), NB=4
// HID1=64, HID2=128

// ---------------- workspace layout (float-slot offsets) ----------------
// x1/yl1/yl2/x2c/H2psi/H2phi/h are bf16.
static constexpr size_t OFF_X1     = 0;          // bf16 2*256*256*64 -> 4194304 slots
static constexpr size_t OFF_YL1    = 4194304;    // bf16 -> 1048576
static constexpr size_t OFF_YL2    = 5242880;    // bf16 -> 262144
static constexpr size_t OFF_HBF    = 5505024;    // bf16 h -> 4194304
static constexpr size_t OFF_H2PSI  = 9699328;    // bf16 32768*128 -> 2097152 (x2c overlays)
static constexpr size_t OFF_H2PHI  = 11796480;   // 2097152
static constexpr size_t OFF_CWTBF  = 13893632;   // 221184
static constexpr size_t OFF_Q1BF   = 14114816;   // 4096
static constexpr size_t OFF_W2T    = 14118912;   // 8*8192 bf16 = 32768 float-slots
static constexpr size_t OFF_GPART  = 14151680;   // 512*8192 f32 = 4194304
static constexpr size_t OFF_SVP    = 18345984;   // 32768
static constexpr size_t OFF_G      = 18378752;   // 16384
static constexpr size_t OFF_SV     = 18395136;   // 128
static constexpr size_t OFF_C      = 18395264;   // 16384
static constexpr size_t OFF_D      = 18411648;   // 128
// end = 18411776 floats (~73.6 MB) <= proven-available 134.3 MB

typedef __attribute__((ext_vector_type(8)))  short bf16x8_t;   // 8 bf16 in 4 VGPRs
typedef __attribute__((ext_vector_type(16))) float f32x16_t;   // 32x32 MFMA acc

// ---------------- helpers ----------------
__device__ inline float wave_sum64(float v) {
    v += __shfl_xor(v, 1);
    v += __shfl_xor(v, 2);
    v += __shfl_xor(v, 4);
    v += __shfl_xor(v, 8);
    v += __shfl_xor(v, 16);
    v += __shfl_xor(v, 32);
    return v;
}

__device__ inline unsigned short f2bf(float f) {   // round-to-nearest-even
    uint32_t u = __float_as_uint(f);
    uint32_t r = u + 0x7FFFu + ((u >> 16) & 1u);
    return (unsigned short)(r >> 16);
}
__device__ inline float bf2f(unsigned short u) {
    return __uint_as_float((uint32_t)u << 16);
}
// 8 bf16 (uint4) -> 8 f32
__device__ inline void bf8_to_f(uint4 u, float* d) {
    unsigned uv[4] = {u.x, u.y, u.z, u.w};
#pragma unroll
    for (int i = 0; i < 4; ++i) {
        d[2 * i]     = __uint_as_float((uv[i] & 0xFFFFu) << 16);
        d[2 * i + 1] = __uint_as_float(uv[i] & 0xFFFF0000u);
    }
}

// full-res flat pixel index of coarse pixel (b, n): n in [0,16384)
__device__ inline size_t fullpix(int b, int n) {
    return (size_t)(b * 65536 + (n >> 7) * 512 + ((n & 127) << 1));
}

struct Lerp { int i0, i1; float f; };
__device__ inline Lerp lcoord(int o, float r, float off, int Sin) {
    float s = fmaxf(fmaf((float)o, r, off), 0.f);
    Lerp L;
    L.i0 = (int)s;
    L.f  = s - (float)L.i0;
    L.i1 = min(L.i0 + 1, Sin - 1);
    return L;
}

// ---------------- fused setup: convW | q1 | W2 frag-order | lift ----------------
// grid 2528: [0,1728) convW; [1728,1760) q1; [1760,2016) W2t; [2016,2528) lift
__global__ __launch_bounds__(256) void k_setup(const float* __restrict__ convW,
                                               unsigned short* __restrict__ cwt,
                                               const float* __restrict__ q1W,
                                               unsigned short* __restrict__ q1bf,
                                               const float* __restrict__ psiW2,
                                               const float* __restrict__ phiW2,
                                               unsigned short* __restrict__ w2t,
                                               const float* __restrict__ x,
                                               const float* __restrict__ a,
                                               const float* __restrict__ pW,
                                               const float* __restrict__ pb,
                                               unsigned short* __restrict__ hbf) {
    int bid = blockIdx.x;
    int t = threadIdx.x;
    if (bid < 1728) {
        // convW[i][l][oc][ic][3][3] f32 -> wt[((il*9+tap)*4+kq)*1024 + hi*512 + oc*8 + j]
        int idx = bid * 256 + t;                  // 442368
        if (idx >= 442368) return;
        int j    = idx & 7;
        int oc   = (idx >> 3) & 63;
        int hi   = (idx >> 9) & 1;
        int kq   = (idx >> 10) & 3;
        int rest = idx >> 12;                     // il*9 + tap
        int tap  = rest % 9;
        int il   = rest / 9;
        int ic   = kq * 16 + hi * 8 + j;
        cwt[idx] = f2bf(convW[((size_t)(il * 64 + oc) * 64 + ic) * 9 + tap]);
    } else if (bid < 1760) {
        int idx = (bid - 1728) * 256 + t;         // 8192
        int k = idx & 63;
        int j = idx >> 6;
        q1bf[j * 64 + k] = f2bf(q1W[k * 128 + j]);
    } else if (bid < 2016) {
        // W2[m][i][64 k][128 j] -> w2t[((((m*4+i)*4+jt)*4+kq)*2+hi)*256 + lo*8 + jj]
        int idx = (bid - 1760) * 256 + t;         // 65536
        int jj = idx & 7;
        int lo = (idx >> 3) & 31;
        int hi = (idx >> 8) & 1;
        int kq = (idx >> 9) & 3;
        int jt = (idx >> 11) & 3;
        int i  = (idx >> 13) & 3;
        int m  = idx >> 15;
        int k  = kq * 16 + hi * 8 + jj;
        int j  = jt * 32 + lo;
        const float* W2 = m ? phiW2 : psiW2;
        w2t[idx] = f2bf(W2[(size_t)i * 8192 + k * 128 + j]);
    } else {
        int p = (bid - 2016) * 256 + t;           // 131072
        float a0 = a[(size_t)p * 2 + 0];
        float a1 = a[(size_t)p * 2 + 1];
        float xv = x[p];
        float vals[64];
#pragma unroll
        for (int c = 0; c < 64; ++c)
            vals[c] = fmaf(a0, pW[c], fmaf(a1, pW[64 + c], fmaf(xv, pW[128 + c], pb[c])));
        unsigned short us[64];
#pragma unroll
        for (int c = 0; c < 64; ++c) us[c] = f2bf(vals[c]);
        unsigned short* bp = hbf + (size_t)p * 64;
#pragma unroll
        for (int c = 0; c < 64; c += 8)
            *(uint4*)(bp + c) = *(uint4*)(us + c);
    }
}

// ---------------- fused conv (blocks 0..1343) + mlp-MFMA (blocks 1344..2367) ----------------
// conv: 16x8 px tile, A-only LDS 23 KB -> ~6 blocks/CU, frag-order B from L2 (reg dbuf).
// mlp:  h1 computed ONCE cooperatively into LDS (reuses Ald, swizzled), then
//       all 4 waves read A-fragments from LDS; W2-GEMM via MFMA; outputs bf16.
__global__ __launch_bounds__(256) void k_convmlp(
    const unsigned short* __restrict__ hbf,   // [2][256][256][64] bf16
    const unsigned short* __restrict__ wbf,   // conv W frag-order, 36864 per (iter,lvl)
    const float* __restrict__ convb,          // [12][64]
    unsigned short* __restrict__ x1, unsigned short* __restrict__ yl1,
    unsigned short* __restrict__ yl2,
    const float* __restrict__ a, const float* __restrict__ x,
    const float* __restrict__ W1a, const float* __restrict__ b1a,
    const float* __restrict__ b2a,
    const float* __restrict__ W1b, const float* __restrict__ b1b,
    const float* __restrict__ b2b,
    const unsigned short* __restrict__ w2t,   // mlp W2 frag-order
    unsigned short* __restrict__ H2a, unsigned short* __restrict__ H2b,
    int iter) {
    __shared__ unsigned short Ald[11520];     // conv: 180 halo px * 64 ic; mlp: h1[64px][64k]
    int bid = blockIdx.x;
    int t = threadIdx.x;

    if (bid >= 1344) {
        // ---------------- mlp path (MFMA, shared h1) ----------------
        int blk = bid - 1344;                      // 0..1023
        int m = blk >> 9;                          // 0=psi, 1=phi
        int px0 = (blk & 511) << 6;                // 64 px per block
        const float* W1 = m ? W1b : W1a;
        const float* b1 = m ? b1b : b1a;
        const float* b2 = m ? b2b : b2a;
        unsigned short* H2 = m ? H2b : H2a;

        // ---- cooperative h1 -> LDS (each thread: 1 px x 16 k), swizzled ----
        {
            int px = t >> 2;                       // 0..63
            int ks = (t & 3) << 4;                 // 0/16/32/48
            int pxl = px0 + px;
            int bb = pxl >> 14;
            size_t ap = fullpix(bb, pxl & 16383);
            float a0 = a[ap * 2], a1 = a[ap * 2 + 1], xv = x[ap];
            unsigned short hv[16];
#pragma unroll
            for (int q = 0; q < 16; ++q) {
                int k = ks + q;
                hv[q] = f2bf(fmaxf(fmaf(a0, W1[k], fmaf(a1, W1[64 + k],
                              fmaf(xv, W1[128 + k], b1[k]))), 0.f));
            }
            int base = px * 128 + ks * 2;          // byte offset in [64px][64k] bf16
            int sw = (px & 7) << 4;
            *(uint4*)((char*)Ald + ((base) ^ sw))      = *(uint4*)hv;
            *(uint4*)((char*)Ald + ((base + 16) ^ sw)) = *(uint4*)(hv + 8);
        }
        __syncthreads();

        int w    = t >> 6;                         // j-tile 0..3
        int lane = t & 63;
        int lo   = lane & 31;
        int hi   = lane >> 5;

        // ---- A-fragments from LDS (k = kq*16 + hi*8 + jj contiguous) ----
        bf16x8_t faA[4], faB[4];
#pragma unroll
        for (int kq = 0; kq < 4; ++kq) {
            int koff = kq * 32 + hi * 16;          // byte offset within row
            int bytesA = (lo * 128 + koff) ^ ((lo & 7) << 4);
            int pxB = 32 + lo;
            int bytesB = (pxB * 128 + koff) ^ ((pxB & 7) << 4);
            faA[kq] = *(bf16x8_t*)((char*)Ald + bytesA);
            faB[kq] = *(bf16x8_t*)((char*)Ald + bytesB);
        }
        const unsigned short* wb =
            w2t + (size_t)(((m * 4 + iter) * 4 + w) * 4) * 512 + hi * 256 + lo * 8;
        f32x16_t accA = {}, accB = {};
#pragma unroll
        for (int kq = 0; kq < 4; ++kq) {
            bf16x8_t fb = *(const bf16x8_t*)(wb + kq * 512);
            accA = __builtin_amdgcn_mfma_f32_32x32x16_bf16(faA[kq], fb, accA, 0, 0, 0);
            accB = __builtin_amdgcn_mfma_f32_32x32x16_bf16(faB[kq], fb, accB, 0, 0, 0);
        }
        float bias2 = b2[w * 32 + lo];
#pragma unroll
        for (int reg = 0; reg < 16; ++reg) {
            int row = (reg & 3) + 8 * (reg >> 2) + 4 * hi;
            H2[(size_t)(px0 + row) * 128 + w * 32 + lo]      = f2bf(fmaxf(accA[reg] + bias2, 0.f));
            H2[(size_t)(px0 + 32 + row) * 128 + w * 32 + lo] = f2bf(fmaxf(accB[reg] + bias2, 0.f));
        }
        return;
    }

    // ---------------- conv path (16 wide x 8 tall tile) ----------------
    int lvl, tix, Sl, st, tpb, tprx;
    if (bid < 1024)      { lvl = 0; tix = bid;        Sl = 256; st = 1; tpb = 512; tprx = 16; }
    else if (bid < 1280) { lvl = 1; tix = bid - 1024; Sl = 128; st = 2; tpb = 128; tprx = 8;  }
    else                 { lvl = 2; tix = bid - 1280; Sl = 64;  st = 4; tpb = 32;  tprx = 4;  }
    int b = tix / tpb;
    int r = tix - b * tpb;
    int y0 = (r / tprx) << 3, x0 = (r % tprx) << 4;

    // ---- stage A: 10x18 halo x 64 ic, zero-padded ----
    for (int c = t; c < 1440; c += 256) {       // 180 rows * 8 slots(16B)
        int lin = c >> 3, slot = c & 7;
        int ty = lin / 18, tx = lin - ty * 18;
        int oy = y0 + ty - 1, ox = x0 + tx - 1;
        uint4 val = make_uint4(0u, 0u, 0u, 0u);
        if ((unsigned)oy < (unsigned)Sl && (unsigned)ox < (unsigned)Sl) {
            const unsigned short* src =
                hbf + (((size_t)(b * 256 + oy * st) * 256 + ox * st) << 6) + (slot << 3);
            val = *(const uint4*)src;
        }
        int byte = (lin << 7) + (((slot ^ (lin & 7))) << 4);
        *(uint4*)((char*)Ald + byte) = val;
    }
    __syncthreads();

    int w    = t >> 6;                          // wave: rows 2w..2w+1 (32 px)
    int lane = t & 63;
    int lo   = lane & 31;
    int hi   = lane >> 5;
    f32x16_t acc00 = {}, acc01 = {};

    const unsigned short* wbase =
        wbf + (size_t)(iter * 3 + lvl) * 36864 + hi * 512 + lo * 8;

    int yA0 = 2 * w + (lo >> 4);
    int xA  = lo & 15;

    bf16x8_t v0c[4], v1c[4], v0n[4], v1n[4];
#pragma unroll
    for (int kq = 0; kq < 4; ++kq) {
        v0c[kq] = *(const bf16x8_t*)(wbase + kq * 1024);
        v1c[kq] = *(const bf16x8_t*)(wbase + kq * 1024 + 256);
    }
#pragma unroll
    for (int tap = 0; tap < 9; ++tap) {
        if (tap < 8) {
#pragma unroll
            for (int kq = 0; kq < 4; ++kq) {
                int keo = ((tap + 1) * 4 + kq) * 1024;
                v0n[kq] = *(const bf16x8_t*)(wbase + keo);
                v1n[kq] = *(const bf16x8_t*)(wbase + keo + 256);
            }
        }
        int dy = tap / 3, dx = tap - dy * 3;
        int lin0 = (yA0 + dy) * 18 + (xA + dx);
#pragma unroll
        for (int kq = 0; kq < 4; ++kq) {
            int icb = (kq << 5) + (hi << 4);            // byte offset in A row
            int a0b = ((lin0 << 7) + icb) ^ ((lin0 & 7) << 4);
            bf16x8_t va0 = *(bf16x8_t*)((char*)Ald + a0b);
            acc00 = __builtin_amdgcn_mfma_f32_32x32x16_bf16(va0, v0c[kq], acc00, 0, 0, 0);
            acc01 = __builtin_amdgcn_mfma_f32_32x32x16_bf16(va0, v1c[kq], acc01, 0, 0, 0);
        }
#pragma unroll
        for (int kq = 0; kq < 4; ++kq) { v0c[kq] = v0n[kq]; v1c[kq] = v1n[kq]; }
    }

    // ---- store bf16 (C layout: col=lo -> oc, row=(reg&3)+8*(reg>>2)+4*hi -> px) ----
    unsigned short* out = (lvl == 0) ? x1 : (lvl == 1 ? yl1 : yl2);
    const float* bias = convb + (iter * 3 + lvl) * 64;
    float bias0 = bias[lo];
    float bias1 = bias[32 + lo];
#pragma unroll
    for (int reg = 0; reg < 16; ++reg) {
        int row = (reg & 3) + 8 * (reg >> 2) + 4 * hi;   // 0..31
        int yt  = 2 * w + (row >> 4);
        int xt  = row & 15;
        size_t pix = ((size_t)(b * Sl + y0 + yt) * Sl + (x0 + xt)) << 6;
        out[pix + lo]      = f2bf(acc00[reg] + bias0);
        out[pix + 32 + lo] = f2bf(acc01[reg] + bias1);
    }
}

// ---------------- split-K stage 1: Gpart[blk] = v^T H2psi over 64 px; svpart ----------------
__global__ __launch_bounds__(256) void k_gpart(const unsigned short* __restrict__ hbf,
                                               const unsigned short* __restrict__ H2psi,
                                               float* __restrict__ Gpart,
                                               float* __restrict__ svpart) {
    __shared__ float vt[4096];       // [64 px][64 w]
    __shared__ float h2t[8192];      // [64 px][128 j]
    int blk = blockIdx.x;            // 512
    int b = blk >> 8;
    int n0 = (blk & 255) << 6;
    int t = threadIdx.x;
    int pxq = t >> 2, qq = t & 3;
    int sw = (pxq & 7) << 4;
    {
        const unsigned short* src = hbf + fullpix(b, n0 + pxq) * 64 + qq * 16;
        uint4 u0 = *(const uint4*)src;
        uint4 u1 = *(const uint4*)(src + 8);
        float f[16];
        bf8_to_f(u0, f);
        bf8_to_f(u1, f + 8);
#pragma unroll
        for (int j = 0; j < 4; ++j) {
            int byte = (pxq * 256 + qq * 64 + j * 16) ^ sw;
            *(float4*)((char*)vt + byte) = make_float4(f[4 * j], f[4 * j + 1],
                                                       f[4 * j + 2], f[4 * j + 3]);
        }
        const unsigned short* hsrc = H2psi + ((size_t)(b * 16384 + n0 + pxq)) * 128 + qq * 32;
#pragma unroll
        for (int rr = 0; rr < 4; ++rr) {
            uint4 hu = *(const uint4*)(hsrc + rr * 8);
            float g[8];
            bf8_to_f(hu, g);
            int byte0 = (pxq * 512 + qq * 128 + rr * 32) ^ sw;
            int byte1 = (pxq * 512 + qq * 128 + rr * 32 + 16) ^ sw;
            *(float4*)((char*)h2t + byte0) = make_float4(g[0], g[1], g[2], g[3]);
            *(float4*)((char*)h2t + byte1) = make_float4(g[4], g[5], g[6], g[7]);
        }
    }
    __syncthreads();

    int wt_ = (t >> 5) << 3;         // 0..56
    int kt  = (t & 31) << 2;         // 0..124
    float acc[8][4];
#pragma unroll
    for (int i = 0; i < 8; ++i)
#pragma unroll
        for (int j = 0; j < 4; ++j) acc[i][j] = 0.f;

#pragma unroll 4
    for (int nn = 0; nn < 64; ++nn) {
        int nsw = (nn & 7) << 4;
        float4 hv = *(float4*)((char*)h2t + ((nn * 512 + kt * 4) ^ nsw));
        float4 v0 = *(float4*)((char*)vt + ((nn * 256 + wt_ * 4) ^ nsw));
        float4 v1 = *(float4*)((char*)vt + ((nn * 256 + wt_ * 4 + 16) ^ nsw));
        float vv[8] = {v0.x, v0.y, v0.z, v0.w, v1.x, v1.y, v1.z, v1.w};
        float hh[4] = {hv.x, hv.y, hv.z, hv.w};
#pragma unroll
        for (int i = 0; i < 8; ++i)
#pragma unroll
            for (int j = 0; j < 4; ++j) acc[i][j] = fmaf(vv[i], hh[j], acc[i][j]);
    }

    float* gp = Gpart + (size_t)blk * 8192;
#pragma unroll
    for (int i = 0; i < 8; ++i)
        *(float4*)&gp[(wt_ + i) * 128 + kt] =
            make_float4(acc[i][0], acc[i][1], acc[i][2], acc[i][3]);

    if (t < 64) {
        float s = 0.f;
#pragma unroll 8
        for (int p = 0; p < 64; ++p)
            s += *(float*)((char*)vt + ((p * 256 + t * 4) ^ ((p & 7) << 4)));
        svpart[blk * 64 + t] = s;
    }
}

// ---------------- reduce: G = sum Gpart; sv = sum svpart (grid 258) ----------------
__global__ __launch_bounds__(256) void k_gred(const float* __restrict__ Gpart,
                                              const float* __restrict__ svpart,
                                              float* __restrict__ G,
                                              float* __restrict__ sv) {
    __shared__ float red[4][64];
    int blk = blockIdx.x;
    int t = threadIdx.x;
    if (blk < 256) {
        int b  = blk >> 7;
        int es = (blk & 127) << 6;
        int e  = es + (t & 63);
        int cg = t >> 6;
        float s = 0.f;
        const float* gp = Gpart + ((size_t)(b * 256 + cg * 64)) * 8192 + e;
#pragma unroll 8
        for (int c = 0; c < 64; ++c) s += gp[(size_t)c * 8192];
        red[cg][t & 63] = s;
        __syncthreads();
        if (t < 64)
            G[b * 8192 + es + t] = red[0][t] + red[1][t] + red[2][t] + red[3][t];
    } else {
        int b = blk - 256;
        int w = t & 63, cg = t >> 6;
        float s = 0.f;
        const float* sp = svpart + ((size_t)(b * 256 + cg * 64)) * 64 + w;
#pragma unroll 8
        for (int c = 0; c < 64; ++c) s += sp[c * 64];
        red[cg][w] = s;
        __syncthreads();
        if (t < 64) sv[b * 64 + t] = red[0][t] + red[1][t] + red[2][t] + red[3][t];
    }
}

// ---------------- yc: ybar -> C[b][w][k], D[b][w] (grid 32) ----------------
__global__ __launch_bounds__(256) void k_yc(const float* __restrict__ G,
                                            const float* __restrict__ sv,
                                            const float* __restrict__ W3psi,
                                            const float* __restrict__ b3psi,
                                            const float* __restrict__ W3phi,
                                            const float* __restrict__ b3phi,
                                            float* __restrict__ C,
                                            float* __restrict__ D) {
    __shared__ float ybar[256];
    int bq = blockIdx.x;             // 32
    int b = bq >> 4, q = bq & 15;
    int t = threadIdx.x;
    {
        int o = t, w = o >> 2;
        const float* gp = &G[(size_t)(b * 64 + w) * 128];
        float s0 = 0.f, s1 = 0.f, s2 = 0.f, s3 = 0.f;
#pragma unroll 4
        for (int k = 0; k < 128; k += 4) {
            s0 = fmaf(W3psi[(k + 0) * 256 + o], gp[k + 0], s0);
            s1 = fmaf(W3psi[(k + 1) * 256 + o], gp[k + 1], s1);
            s2 = fmaf(W3psi[(k + 2) * 256 + o], gp[k + 2], s2);
            s3 = fmaf(W3psi[(k + 3) * 256 + o], gp[k + 3], s3);
        }
        float s = b3psi[o] * sv[b * 64 + w] + ((s0 + s1) + (s2 + s3));
        ybar[o] = s * (1.f / 16384.f);
    }
    __syncthreads();
#pragma unroll
    for (int rep = 0; rep < 2; ++rep) {
        int e = q * 512 + rep * 256 + t;   // slice of 8192
        int w = e >> 7, k = e & 127;
        const float* wp = &W3phi[k * 256 + w * 4];
        C[b * 8192 + e] = fmaf(wp[0], ybar[w * 4],
                          fmaf(wp[1], ybar[w * 4 + 1],
                          fmaf(wp[2], ybar[w * 4 + 2], wp[3] * ybar[w * 4 + 3])));
    }
    if (q == 0 && t < 64) {
        int w = t;
        D[b * 64 + w] = b3phi[w * 4] * ybar[w * 4] + b3phi[w * 4 + 1] * ybar[w * 4 + 1]
                      + b3phi[w * 4 + 2] * ybar[w * 4 + 2] + b3phi[w * 4 + 3] * ybar[w * 4 + 3];
    }
}

// ---------------- x2c: x2c[px][w] = H2phi[px][:].C[b][w][:] + D[b][w] (grid 1024) ----------------
__global__ __launch_bounds__(256) void k_x2c(const unsigned short* __restrict__ H2phi,
                                             const float* __restrict__ C,
                                             const float* __restrict__ D,
                                             unsigned short* __restrict__ x2c) {
    __shared__ float cl[8192];       // C[b]: [64 w][128 k] (32 KB)
    __shared__ float h2l[4096];      // [32 px][128 k], XOR-swizzled (16 KB)
    __shared__ float Dl[64];
    int blk = blockIdx.x;            // 1024: 512 per b
    int b = blk >> 9;
    int px0 = (blk & 511) << 5;      // 32 px per block
    int t = threadIdx.x;

    const float* cp = C + b * 8192;
#pragma unroll
    for (int r = 0; r < 8; ++r) {
        int f = r * 1024 + t * 4;
        *(float4*)&cl[f] = *(const float4*)&cp[f];
    }
    if (t < 64) Dl[t] = D[b * 64 + t];
    {   // stage H2phi tile (bf16 -> f32), swizzled
        const unsigned short* hsrc = H2phi + ((size_t)(b * 16384 + px0)) * 128;
#pragma unroll
        for (int r = 0; r < 2; ++r) {
            int f = r * 2048 + t * 8;              // float index, 8 per rep
            uint4 u = *(const uint4*)(hsrc + f);
            float d[8];
            bf8_to_f(u, d);
            int px = f >> 7;
            int sw2 = ((px & 7) << 4) ^ (((px >> 3) & 1) << 6);
            *(float4*)((char*)h2l + ((f * 4) ^ sw2))      = make_float4(d[0], d[1], d[2], d[3]);
            *(float4*)((char*)h2l + ((f * 4 + 16) ^ sw2)) = make_float4(d[4], d[5], d[6], d[7]);
        }
    }
    __syncthreads();

    int px = t & 31;
    int w0 = (t >> 5) << 3;          // 0..56: 8 w per thread
    int psw = ((px & 7) << 4) ^ (((px >> 3) & 1) << 6);
    float acc[8];
#pragma unroll
    for (int j = 0; j < 8; ++j) acc[j] = 0.f;

#pragma unroll 4
    for (int kq = 0; kq < 32; ++kq) {
        float4 hq = *(float4*)((char*)h2l + ((px * 512 + kq * 16) ^ psw));
#pragma unroll
        for (int j = 0; j < 8; ++j) {
            float4 cq = *(float4*)&cl[(w0 + j) * 128 + kq * 4];
            acc[j] = fmaf(hq.x, cq.x, acc[j]);
            acc[j] = fmaf(hq.y, cq.y, acc[j]);
            acc[j] = fmaf(hq.z, cq.z, acc[j]);
            acc[j] = fmaf(hq.w, cq.w, acc[j]);
        }
    }
    unsigned short us[8];
#pragma unroll
    for (int j = 0; j < 8; ++j) us[j] = f2bf(acc[j] + Dl[w0 + j]);
    unsigned short* op = x2c + ((size_t)(b * 16384 + px0 + px)) * 64 + w0;
    *(uint4*)op = *(uint4*)us;
}

// ---------------- epilogue: h = LN(x1 + up(yl1) + up(yl2) + up(x2c)); bf16 in/out ----------------
__global__ __launch_bounds__(256) void k_epilogue(const unsigned short* __restrict__ x1,
                                                  const unsigned short* __restrict__ yl1,
                                                  const unsigned short* __restrict__ yl2,
                                                  const unsigned short* __restrict__ x2c,
                                                  const float* __restrict__ lnG,
                                                  const float* __restrict__ lnB,
                                                  unsigned short* __restrict__ hbf,
                                                  int do_relu) {
    __shared__ float y1s[2][10][64];   // yl1 corners (scale 2)
    __shared__ float xcs[2][10][64];   // x2c corners (scale 2)
    __shared__ float y2s[2][6][64];    // yl2 corners (scale 4)
    int t    = threadIdx.x;
    int blk  = blockIdx.x;                 // 8192 = 2 * 256 * 16
    int b    = blk >> 12;
    int rest = blk & 4095;
    int y    = rest >> 4;
    int x0   = (rest & 15) << 4;
    int wv = t >> 6, lane = t & 63;

    Lerp ly1 = lcoord(y, 0.5f, -0.25f, 128);    // yl1 & x2c
    Lerp ly2 = lcoord(y, 0.25f, -0.375f, 64);   // yl2
    int c1 = max(0, (int)floorf((float)x0 * 0.5f - 0.25f));
    int c2 = max(0, (int)floorf((float)x0 * 0.25f - 0.375f));

    const unsigned short* Y1 = yl1 + (size_t)b * 16384 * 64;
    const unsigned short* Y2 = yl2 + (size_t)b * 4096 * 64;
    const unsigned short* XC = x2c + (size_t)b * 16384 * 64;
    for (int f4 = t; f4 < 832; f4 += 256) {
        int e, row, col;
        const unsigned short* src;
        float* dst;
        if (f4 < 320) {                 // y1s
            e = f4 * 4;
            int r = e / 640, rm = e - r * 640;
            int j = rm >> 6, ch = rm & 63;
            row = r ? ly1.i1 : ly1.i0;
            col = min(c1 + j, 127);
            src = &Y1[((size_t)(row * 128 + col)) * 64 + ch];
            dst = &y1s[r][j][ch];
        } else if (f4 < 640) {          // xcs
            e = (f4 - 320) * 4;
            int r = e / 640, rm = e - r * 640;
            int j = rm >> 6, ch = rm & 63;
            row = r ? ly1.i1 : ly1.i0;
            col = min(c1 + j, 127);
            src = &XC[((size_t)(row * 128 + col)) * 64 + ch];
            dst = &xcs[r][j][ch];
        } else {                        // y2s
            e = (f4 - 640) * 4;
            int r = e / 384, rm = e - r * 384;
            int j = rm >> 6, ch = rm & 63;
            row = r ? ly2.i1 : ly2.i0;
            col = min(c2 + j, 63);
            src = &Y2[((size_t)(row * 64 + col)) * 64 + ch];
            dst = &y2s[r][j][ch];
        }
        uint2 u = *(const uint2*)src;   // 4 bf16
        dst[0] = __uint_as_float((u.x & 0xFFFFu) << 16);
        dst[1] = __uint_as_float(u.x & 0xFFFF0000u);
        dst[2] = __uint_as_float((u.y & 0xFFFFu) << 16);
        dst[3] = __uint_as_float(u.y & 0xFFFF0000u);
    }
    __syncthreads();

    float g = lnG[lane], be = lnB[lane];
    for (int pp = 0; pp < 4; ++pp) {
        int xx = x0 + wv * 4 + pp;
        size_t pix = (size_t)((b * 256 + y) * 256 + xx);
        float v = bf2f(x1[pix * 64 + lane]);
        {   // yl1 + x2c (shared x-lerp)
            Lerp lx = lcoord(xx, 0.5f, -0.25f, 128);
            int j0 = lx.i0 - c1, j1 = lx.i1 - c1;
            float a0 = y1s[0][j0][lane], a1 = y1s[0][j1][lane];
            float b0 = y1s[1][j0][lane], b1 = y1s[1][j1][lane];
            float ta = a0 + lx.f * (a1 - a0);
            float tb = b0 + lx.f * (b1 - b0);
            v += ta + ly1.f * (tb - ta);
            float p0 = xcs[0][j0][lane], p1 = xcs[0][j1][lane];
            float q0 = xcs[1][j0][lane], q1 = xcs[1][j1][lane];
            float tp = p0 + lx.f * (p1 - p0);
            float tq = q0 + lx.f * (q1 - q0);
            v += tp + ly1.f * (tq - tp);
        }
        {   // yl2
            Lerp lx = lcoord(xx, 0.25f, -0.375f, 64);
            int j0 = lx.i0 - c2, j1 = lx.i1 - c2;
            float a0 = y2s[0][j0][lane], a1 = y2s[0][j1][lane];
            float b0 = y2s[1][j0][lane], b1 = y2s[1][j1][lane];
            float ta = a0 + lx.f * (a1 - a0);
            float tb = b0 + lx.f * (b1 - b0);
            v += ta + ly2.f * (tb - ta);
        }
        float mu  = wave_sum64(v) * (1.f / 64.f);
        float d   = v - mu;
        float var = wave_sum64(d * d) * (1.f / 64.f);
        float ov  = fmaf(d * rsqrtf(var + 1e-5f), g, be);
        if (do_relu) ov = fmaxf(ov, 0.f);
        hbf[pix * 64 + lane] = f2bf(ov);
    }
}

// ---------------- head (MFMA): out = relu(hbf@q1W+q1b) . q2 + q2b ----------------
__global__ __launch_bounds__(256) void k_head_mfma(
    const unsigned short* __restrict__ hbf,   // [131072][64] bf16
    const unsigned short* __restrict__ q1bf,  // [128 j][64 k] bf16
    const float* __restrict__ q1b,            // [128]
    const float* __restrict__ q2,             // [128]
    const float* __restrict__ q2b,            // [1]
    float* __restrict__ out) {
    __shared__ unsigned short Q[8192];        // [j][k] swizzled
    int t = threadIdx.x;
    for (int c = t; c < 1024; c += 256) {
        int j = c >> 3, slot = c & 7;
        uint4 v = *(const uint4*)(q1bf + j * 64 + slot * 8);
        int byte = (j * 128 + slot * 16) ^ ((j & 7) << 4);
        *(uint4*)((char*)Q + byte) = v;
    }
    __syncthreads();

    int w = t >> 6, lane = t & 63;
    int lo = lane & 31, hi = lane >> 5;
    int px0 = blockIdx.x * 128 + w * 32;      // grid 1024

    bf16x8_t av[4];
    const unsigned short* hp = hbf + (size_t)(px0 + lo) * 64 + hi * 8;
#pragma unroll
    for (int ks = 0; ks < 4; ++ks)
        av[ks] = *(const bf16x8_t*)(hp + ks * 16);

    float res[16];
#pragma unroll
    for (int r = 0; r < 16; ++r) res[r] = 0.f;

#pragma unroll
    for (int jb = 0; jb < 4; ++jb) {
        f32x16_t acc = {};
        int j = jb * 32 + lo;
#pragma unroll
        for (int ks = 0; ks < 4; ++ks) {
            int byte = (j * 128 + ks * 32 + hi * 16) ^ ((j & 7) << 4);
            bf16x8_t bv = *(bf16x8_t*)((char*)Q + byte);
            acc = __builtin_amdgcn_mfma_f32_32x32x16_bf16(av[ks], bv, acc, 0, 0, 0);
        }
        float b1 = q1b[j];
        float w2 = q2[j];
#pragma unroll
        for (int r = 0; r < 16; ++r)
            res[r] = fmaf(fmaxf(acc[r] + b1, 0.f), w2, res[r]);
    }
#pragma unroll
    for (int r = 0; r < 16; ++r) {
        float v = res[r];
        v += __shfl_xor(v, 1);
        v += __shfl_xor(v, 2);
        v += __shfl_xor(v, 4);
        v += __shfl_xor(v, 8);
        v += __shfl_xor(v, 16);
        res[r] = v;
    }
    if (lo == 0) {
        float qb = q2b[0];
#pragma unroll
        for (int r = 0; r < 16; ++r) {
            int row = (r & 3) + 8 * (r >> 2) + 4 * hi;
            out[px0 + row] = res[r] + qb;
        }
    }
}

// ---------------- launch ----------------
extern "C" void kernel_launch(void* const* d_in, const int* in_sizes, int n_in,
                              void* d_out, int out_size, void* d_ws, size_t ws_size,
                              hipStream_t stream) {
    const float* x     = (const float*)d_in[0];
    const float* a     = (const float*)d_in[1];
    const float* pW    = (const float*)d_in[2];
    const float* pb    = (const float*)d_in[3];
    const float* q1W   = (const float*)d_in[4];
    const float* q1b   = (const float*)d_in[5];
    const float* q2W   = (const float*)d_in[6];
    const float* q2b   = (const float*)d_in[7];
    const float* phiW1 = (const float*)d_in[8];
    const float* phib1 = (const float*)d_in[9];
    const float* phiW2 = (const float*)d_in[10];
    const float* phib2 = (const float*)d_in[11];
    const float* phiW3 = (const float*)d_in[12];
    const float* phib3 = (const float*)d_in[13];
    const float* psiW1 = (const float*)d_in[14];
    const float* psib1 = (const float*)d_in[15];
    const float* psiW2 = (const float*)d_in[16];
    const float* psib2 = (const float*)d_in[17];
    const float* psiW3 = (const float*)d_in[18];
    const float* psib3 = (const float*)d_in[19];
    const float* lnG   = (const float*)d_in[20];
    const float* lnB   = (const float*)d_in[21];
    const float* convW = (const float*)d_in[22];
    const float* convb = (const float*)d_in[23];

    float* ws = (float*)d_ws;
    unsigned short* x1    = (unsigned short*)(ws + OFF_X1);
    unsigned short* yl1   = (unsigned short*)(ws + OFF_YL1);
    unsigned short* yl2   = (unsigned short*)(ws + OFF_YL2);
    unsigned short* hbf   = (unsigned short*)(ws + OFF_HBF);
    unsigned short* H2psi = (unsigned short*)(ws + OFF_H2PSI);
    unsigned short* x2c   = (unsigned short*)(ws + OFF_H2PSI);  // overlay: H2psi dead after k_gpart
    unsigned short* H2phi = (unsigned short*)(ws + OFF_H2PHI);
    unsigned short* cwtbf = (unsigned short*)(ws + OFF_CWTBF);
    unsigned short* q1bf  = (unsigned short*)(ws + OFF_Q1BF);
    unsigned short* w2t   = (unsigned short*)(ws + OFF_W2T);
    float* Gpart = ws + OFF_GPART;
    float* svpart= ws + OFF_SVP;
    float* G     = ws + OFF_G;
    float* sv    = ws + OFF_SV;
    float* C     = ws + OFF_C;
    float* D     = ws + OFF_D;

    k_setup<<<2528, 256, 0, stream>>>(convW, cwtbf, q1W, q1bf,
                                      psiW2, phiW2, w2t, x, a, pW, pb, hbf);

    for (int i = 0; i < 4; ++i) {
        k_convmlp<<<2368, 256, 0, stream>>>(hbf, cwtbf, convb, x1, yl1, yl2,
                                            a, x,
                                            psiW1 + i * 192, psib1 + i * 64, psib2 + i * 128,
                                            phiW1 + i * 192, phib1 + i * 64, phib2 + i * 128,
                                            w2t, H2psi, H2phi, i);
        k_gpart<<<512, 256, 0, stream>>>(hbf, H2psi, Gpart, svpart);
        k_gred<<<258, 256, 0, stream>>>(Gpart, svpart, G, sv);
        k_yc<<<32, 256, 0, stream>>>(G, sv,
                                     psiW3 + (size_t)i * 32768, psib3 + i * 256,
                                     phiW3 + (size_t)i * 32768, phib3 + i * 256,
                                     C, D);
        k_x2c<<<1024, 256, 0, stream>>>(H2phi, C, D, x2c);
        k_epilogue<<<8192, 256, 0, stream>>>(x1, yl1, yl2, x2c,
                                             lnG + i * 64, lnB + i * 64,
                                             hbf, (i < 3) ? 1 : 0);
    }

    k_head_mfma<<<1024, 256, 0, stream>>>(hbf, q1bf, q1b, q2W, q2b, (float*)d_out);
}

// Round 21
// 385.447 us; speedup vs baseline: 1.2170x; 1.0574x over previous
//
#include <hip/hip_runtime.h>
#include <cstddef>
#include <cstdint>

// ---------------- problem constants ----------------
// b=2, s=256, WIDTH=64, RANK=4, CLEVEL=1 (c=2), MLEVEL=2 (L=3), NB=4
// HID1=64, HID2=128

// ---------------- workspace layout (float-slot offsets) ----------------
// x1/yl1/yl2/x2c/H2psi/H2phi/h are bf16.
static constexpr size_t OFF_X1     = 0;          // bf16 2*256*256*64 -> 4194304 slots
static constexpr size_t OFF_YL1    = 4194304;    // bf16 -> 1048576
static constexpr size_t OFF_YL2    = 5242880;    // bf16 -> 262144
static constexpr size_t OFF_HBF    = 5505024;    // bf16 h -> 4194304
static constexpr size_t OFF_H2PSI  = 9699328;    // bf16 32768*128 -> 2097152 (x2c overlays)
static constexpr size_t OFF_H2PHI  = 11796480;   // 2097152
static constexpr size_t OFF_CWTBF  = 13893632;   // 221184
static constexpr size_t OFF_Q1BF   = 14114816;   // 4096
static constexpr size_t OFF_W2T    = 14118912;   // 8*8192 bf16 = 32768 float-slots
static constexpr size_t OFF_GPART  = 14151680;   // 512*8192 f32 = 4194304
static constexpr size_t OFF_SVP    = 18345984;   // 32768
static constexpr size_t OFF_G      = 18378752;   // 16384
static constexpr size_t OFF_SV     = 18395136;   // 128
static constexpr size_t OFF_C      = 18395264;   // 16384
static constexpr size_t OFF_D      = 18411648;   // 128
// end = 18411776 floats (~73.6 MB) <= proven-available 134.3 MB

typedef __attribute__((ext_vector_type(8)))  short bf16x8_t;   // 8 bf16 in 4 VGPRs
typedef __attribute__((ext_vector_type(16))) float f32x16_t;   // 32x32 MFMA acc

// ---------------- helpers ----------------
__device__ inline float wave_sum64(float v) {
    v += __shfl_xor(v, 1);
    v += __shfl_xor(v, 2);
    v += __shfl_xor(v, 4);
    v += __shfl_xor(v, 8);
    v += __shfl_xor(v, 16);
    v += __shfl_xor(v, 32);
    return v;
}

__device__ inline unsigned short f2bf(float f) {   // round-to-nearest-even
    uint32_t u = __float_as_uint(f);
    uint32_t r = u + 0x7FFFu + ((u >> 16) & 1u);
    return (unsigned short)(r >> 16);
}
__device__ inline float bf2f(unsigned short u) {
    return __uint_as_float((uint32_t)u << 16);
}
// 8 bf16 (uint4) -> 8 f32 (memory order)
__device__ inline void bf8_to_f(uint4 u, float* d) {
    unsigned uv[4] = {u.x, u.y, u.z, u.w};
#pragma unroll
    for (int i = 0; i < 4; ++i) {
        d[2 * i]     = __uint_as_float((uv[i] & 0xFFFFu) << 16);
        d[2 * i + 1] = __uint_as_float(uv[i] & 0xFFFF0000u);
    }
}

// full-res flat pixel index of coarse pixel (b, n): n in [0,16384)
__device__ inline size_t fullpix(int b, int n) {
    return (size_t)(b * 65536 + (n >> 7) * 512 + ((n & 127) << 1));
}

struct Lerp { int i0, i1; float f; };
__device__ inline Lerp lcoord(int o, float r, float off, int Sin) {
    float s = fmaxf(fmaf((float)o, r, off), 0.f);
    Lerp L;
    L.i0 = (int)s;
    L.f  = s - (float)L.i0;
    L.i1 = min(L.i0 + 1, Sin - 1);
    return L;
}

// ---------------- fused setup: convW | q1 | W2 frag-order | lift ----------------
// grid 2528: [0,1728) convW; [1728,1760) q1; [1760,2016) W2t; [2016,2528) lift
__global__ __launch_bounds__(256) void k_setup(const float* __restrict__ convW,
                                               unsigned short* __restrict__ cwt,
                                               const float* __restrict__ q1W,
                                               unsigned short* __restrict__ q1bf,
                                               const float* __restrict__ psiW2,
                                               const float* __restrict__ phiW2,
                                               unsigned short* __restrict__ w2t,
                                               const float* __restrict__ x,
                                               const float* __restrict__ a,
                                               const float* __restrict__ pW,
                                               const float* __restrict__ pb,
                                               unsigned short* __restrict__ hbf) {
    int bid = blockIdx.x;
    int t = threadIdx.x;
    if (bid < 1728) {
        // convW[i][l][oc][ic][3][3] f32 -> wt[((il*9+tap)*4+kq)*1024 + hi*512 + oc*8 + j]
        int idx = bid * 256 + t;                  // 442368
        if (idx >= 442368) return;
        int j    = idx & 7;
        int oc   = (idx >> 3) & 63;
        int hi   = (idx >> 9) & 1;
        int kq   = (idx >> 10) & 3;
        int rest = idx >> 12;                     // il*9 + tap
        int tap  = rest % 9;
        int il   = rest / 9;
        int ic   = kq * 16 + hi * 8 + j;
        cwt[idx] = f2bf(convW[((size_t)(il * 64 + oc) * 64 + ic) * 9 + tap]);
    } else if (bid < 1760) {
        int idx = (bid - 1728) * 256 + t;         // 8192
        int k = idx & 63;
        int j = idx >> 6;
        q1bf[j * 64 + k] = f2bf(q1W[k * 128 + j]);
    } else if (bid < 2016) {
        // W2[m][i][64 k][128 j] -> w2t[((((m*4+i)*4+jt)*4+kq)*2+hi)*256 + lo*8 + jj]
        int idx = (bid - 1760) * 256 + t;         // 65536
        int jj = idx & 7;
        int lo = (idx >> 3) & 31;
        int hi = (idx >> 8) & 1;
        int kq = (idx >> 9) & 3;
        int jt = (idx >> 11) & 3;
        int i  = (idx >> 13) & 3;
        int m  = idx >> 15;
        int k  = kq * 16 + hi * 8 + jj;
        int j  = jt * 32 + lo;
        const float* W2 = m ? phiW2 : psiW2;
        w2t[idx] = f2bf(W2[(size_t)i * 8192 + k * 128 + j]);
    } else {
        int p = (bid - 2016) * 256 + t;           // 131072
        float a0 = a[(size_t)p * 2 + 0];
        float a1 = a[(size_t)p * 2 + 1];
        float xv = x[p];
        float vals[64];
#pragma unroll
        for (int c = 0; c < 64; ++c)
            vals[c] = fmaf(a0, pW[c], fmaf(a1, pW[64 + c], fmaf(xv, pW[128 + c], pb[c])));
        unsigned short us[64];
#pragma unroll
        for (int c = 0; c < 64; ++c) us[c] = f2bf(vals[c]);
        unsigned short* bp = hbf + (size_t)p * 64;
#pragma unroll
        for (int c = 0; c < 64; c += 8)
            *(uint4*)(bp + c) = *(uint4*)(us + c);
    }
}

// ---------------- fused conv (blocks 0..1343) + mlp-MFMA (blocks 1344..2367) ----------------
// conv: 16x8 px tile, A-only LDS 23 KB -> ~6 blocks/CU, frag-order B from L2 (reg dbuf).
// mlp:  h1 computed ONCE cooperatively into LDS (reuses Ald, swizzled), then
//       all 4 waves read A-fragments from LDS; W2-GEMM via MFMA; outputs bf16.
__global__ __launch_bounds__(256) void k_convmlp(
    const unsigned short* __restrict__ hbf,   // [2][256][256][64] bf16
    const unsigned short* __restrict__ wbf,   // conv W frag-order, 36864 per (iter,lvl)
    const float* __restrict__ convb,          // [12][64]
    unsigned short* __restrict__ x1, unsigned short* __restrict__ yl1,
    unsigned short* __restrict__ yl2,
    const float* __restrict__ a, const float* __restrict__ x,
    const float* __restrict__ W1a, const float* __restrict__ b1a,
    const float* __restrict__ b2a,
    const float* __restrict__ W1b, const float* __restrict__ b1b,
    const float* __restrict__ b2b,
    const unsigned short* __restrict__ w2t,   // mlp W2 frag-order
    unsigned short* __restrict__ H2a, unsigned short* __restrict__ H2b,
    int iter) {
    __shared__ unsigned short Ald[11520];     // conv: 180 halo px * 64 ic; mlp: h1[64px][64k]
    int bid = blockIdx.x;
    int t = threadIdx.x;

    if (bid >= 1344) {
        // ---------------- mlp path (MFMA, shared h1) ----------------
        int blk = bid - 1344;                      // 0..1023
        int m = blk >> 9;                          // 0=psi, 1=phi
        int px0 = (blk & 511) << 6;                // 64 px per block
        const float* W1 = m ? W1b : W1a;
        const float* b1 = m ? b1b : b1a;
        const float* b2 = m ? b2b : b2a;
        unsigned short* H2 = m ? H2b : H2a;

        // ---- cooperative h1 -> LDS (each thread: 1 px x 16 k), swizzled ----
        {
            int px = t >> 2;                       // 0..63
            int ks = (t & 3) << 4;                 // 0/16/32/48
            int pxl = px0 + px;
            int bb = pxl >> 14;
            size_t ap = fullpix(bb, pxl & 16383);
            float a0 = a[ap * 2], a1 = a[ap * 2 + 1], xv = x[ap];
            unsigned short hv[16];
#pragma unroll
            for (int q = 0; q < 16; ++q) {
                int k = ks + q;
                hv[q] = f2bf(fmaxf(fmaf(a0, W1[k], fmaf(a1, W1[64 + k],
                              fmaf(xv, W1[128 + k], b1[k]))), 0.f));
            }
            int base = px * 128 + ks * 2;          // byte offset in [64px][64k] bf16
            int sw = (px & 7) << 4;
            *(uint4*)((char*)Ald + ((base) ^ sw))      = *(uint4*)hv;
            *(uint4*)((char*)Ald + ((base + 16) ^ sw)) = *(uint4*)(hv + 8);
        }
        __syncthreads();

        int w    = t >> 6;                         // j-tile 0..3
        int lane = t & 63;
        int lo   = lane & 31;
        int hi   = lane >> 5;

        // ---- A-fragments from LDS (k = kq*16 + hi*8 + jj contiguous) ----
        bf16x8_t faA[4], faB[4];
#pragma unroll
        for (int kq = 0; kq < 4; ++kq) {
            int koff = kq * 32 + hi * 16;          // byte offset within row
            int bytesA = (lo * 128 + koff) ^ ((lo & 7) << 4);
            int pxB = 32 + lo;
            int bytesB = (pxB * 128 + koff) ^ ((pxB & 7) << 4);
            faA[kq] = *(bf16x8_t*)((char*)Ald + bytesA);
            faB[kq] = *(bf16x8_t*)((char*)Ald + bytesB);
        }
        const unsigned short* wb =
            w2t + (size_t)(((m * 4 + iter) * 4 + w) * 4) * 512 + hi * 256 + lo * 8;
        f32x16_t accA = {}, accB = {};
#pragma unroll
        for (int kq = 0; kq < 4; ++kq) {
            bf16x8_t fb = *(const bf16x8_t*)(wb + kq * 512);
            accA = __builtin_amdgcn_mfma_f32_32x32x16_bf16(faA[kq], fb, accA, 0, 0, 0);
            accB = __builtin_amdgcn_mfma_f32_32x32x16_bf16(faB[kq], fb, accB, 0, 0, 0);
        }
        float bias2 = b2[w * 32 + lo];
#pragma unroll
        for (int reg = 0; reg < 16; ++reg) {
            int row = (reg & 3) + 8 * (reg >> 2) + 4 * hi;
            H2[(size_t)(px0 + row) * 128 + w * 32 + lo]      = f2bf(fmaxf(accA[reg] + bias2, 0.f));
            H2[(size_t)(px0 + 32 + row) * 128 + w * 32 + lo] = f2bf(fmaxf(accB[reg] + bias2, 0.f));
        }
        return;
    }

    // ---------------- conv path (16 wide x 8 tall tile) ----------------
    int lvl, tix, Sl, st, tpb, tprx;
    if (bid < 1024)      { lvl = 0; tix = bid;        Sl = 256; st = 1; tpb = 512; tprx = 16; }
    else if (bid < 1280) { lvl = 1; tix = bid - 1024; Sl = 128; st = 2; tpb = 128; tprx = 8;  }
    else                 { lvl = 2; tix = bid - 1280; Sl = 64;  st = 4; tpb = 32;  tprx = 4;  }
    int b = tix / tpb;
    int r = tix - b * tpb;
    int y0 = (r / tprx) << 3, x0 = (r % tprx) << 4;

    // ---- stage A: 10x18 halo x 64 ic, zero-padded ----
    for (int c = t; c < 1440; c += 256) {       // 180 rows * 8 slots(16B)
        int lin = c >> 3, slot = c & 7;
        int ty = lin / 18, tx = lin - ty * 18;
        int oy = y0 + ty - 1, ox = x0 + tx - 1;
        uint4 val = make_uint4(0u, 0u, 0u, 0u);
        if ((unsigned)oy < (unsigned)Sl && (unsigned)ox < (unsigned)Sl) {
            const unsigned short* src =
                hbf + (((size_t)(b * 256 + oy * st) * 256 + ox * st) << 6) + (slot << 3);
            val = *(const uint4*)src;
        }
        int byte = (lin << 7) + (((slot ^ (lin & 7))) << 4);
        *(uint4*)((char*)Ald + byte) = val;
    }
    __syncthreads();

    int w    = t >> 6;                          // wave: rows 2w..2w+1 (32 px)
    int lane = t & 63;
    int lo   = lane & 31;
    int hi   = lane >> 5;
    f32x16_t acc00 = {}, acc01 = {};

    const unsigned short* wbase =
        wbf + (size_t)(iter * 3 + lvl) * 36864 + hi * 512 + lo * 8;

    int yA0 = 2 * w + (lo >> 4);
    int xA  = lo & 15;

    bf16x8_t v0c[4], v1c[4], v0n[4], v1n[4];
#pragma unroll
    for (int kq = 0; kq < 4; ++kq) {
        v0c[kq] = *(const bf16x8_t*)(wbase + kq * 1024);
        v1c[kq] = *(const bf16x8_t*)(wbase + kq * 1024 + 256);
    }
#pragma unroll
    for (int tap = 0; tap < 9; ++tap) {
        if (tap < 8) {
#pragma unroll
            for (int kq = 0; kq < 4; ++kq) {
                int keo = ((tap + 1) * 4 + kq) * 1024;
                v0n[kq] = *(const bf16x8_t*)(wbase + keo);
                v1n[kq] = *(const bf16x8_t*)(wbase + keo + 256);
            }
        }
        int dy = tap / 3, dx = tap - dy * 3;
        int lin0 = (yA0 + dy) * 18 + (xA + dx);
#pragma unroll
        for (int kq = 0; kq < 4; ++kq) {
            int icb = (kq << 5) + (hi << 4);            // byte offset in A row
            int a0b = ((lin0 << 7) + icb) ^ ((lin0 & 7) << 4);
            bf16x8_t va0 = *(bf16x8_t*)((char*)Ald + a0b);
            acc00 = __builtin_amdgcn_mfma_f32_32x32x16_bf16(va0, v0c[kq], acc00, 0, 0, 0);
            acc01 = __builtin_amdgcn_mfma_f32_32x32x16_bf16(va0, v1c[kq], acc01, 0, 0, 0);
        }
#pragma unroll
        for (int kq = 0; kq < 4; ++kq) { v0c[kq] = v0n[kq]; v1c[kq] = v1n[kq]; }
    }

    // ---- store bf16 (C layout: col=lo -> oc, row=(reg&3)+8*(reg>>2)+4*hi -> px) ----
    unsigned short* out = (lvl == 0) ? x1 : (lvl == 1 ? yl1 : yl2);
    const float* bias = convb + (iter * 3 + lvl) * 64;
    float bias0 = bias[lo];
    float bias1 = bias[32 + lo];
#pragma unroll
    for (int reg = 0; reg < 16; ++reg) {
        int row = (reg & 3) + 8 * (reg >> 2) + 4 * hi;   // 0..31
        int yt  = 2 * w + (row >> 4);
        int xt  = row & 15;
        size_t pix = ((size_t)(b * Sl + y0 + yt) * Sl + (x0 + xt)) << 6;
        out[pix + lo]      = f2bf(acc00[reg] + bias0);
        out[pix + 32 + lo] = f2bf(acc01[reg] + bias1);
    }
}

// ---------------- split-K stage 1 (MFMA): Gpart[blk][64w][128k] over 64 px; svpart ----------------
// Both operands staged TRANSPOSED (n-contiguous) in LDS; G = v^T . H2psi via 8 MFMA/wave.
__global__ __launch_bounds__(256) void k_gpart(const unsigned short* __restrict__ hbf,
                                               const unsigned short* __restrict__ H2psi,
                                               float* __restrict__ Gpart,
                                               float* __restrict__ svpart) {
    __shared__ unsigned short vtT[4096];    // [64 w][64 n] bf16, XOR-swizzled (8 KB)
    __shared__ unsigned short h2tT[8192];   // [128 k][64 n] bf16, XOR-swizzled (16 KB)
    int blk = blockIdx.x;            // 512
    int b = blk >> 8;
    int n0 = (blk & 255) << 6;
    int t = threadIdx.x;

    // ---- transpose-stage: thread = (pixel n = t>>2, quarter q = t&3) ----
    {
        int n = t >> 2, q = t & 3;
        const unsigned short* src = hbf + fullpix(b, n0 + n) * 64 + q * 16;
        unsigned short vv[16];
        *(uint4*)vv       = *(const uint4*)src;
        *(uint4*)(vv + 8) = *(const uint4*)(src + 8);
#pragma unroll
        for (int i = 0; i < 16; ++i) {
            int w = q * 16 + i;
            int byte = (w * 128 + n * 2) ^ ((w & 7) << 4);
            *(unsigned short*)((char*)vtT + byte) = vv[i];
        }
        const unsigned short* hsrc = H2psi + ((size_t)(b * 16384 + n0 + n)) * 128 + q * 32;
        unsigned short hh[32];
#pragma unroll
        for (int r = 0; r < 4; ++r)
            *(uint4*)(hh + r * 8) = *(const uint4*)(hsrc + r * 8);
#pragma unroll
        for (int i = 0; i < 32; ++i) {
            int k = q * 32 + i;
            int byte = (k * 128 + n * 2) ^ ((k & 7) << 4);
            *(unsigned short*)((char*)h2tT + byte) = hh[i];
        }
    }
    __syncthreads();

    int w    = t >> 6;               // wave id
    int lane = t & 63;
    int lo   = lane & 31;
    int hi   = lane >> 5;
    int w0 = (w & 1) * 32;           // row-tile base (w index)
    int c0 = (w >> 1) * 2;           // first of 2 col-tiles

    // A-frags (row-tile shared by both col-tiles): A[w][n-slice] from vtT
    bf16x8_t fa[4];
#pragma unroll
    for (int kq = 0; kq < 4; ++kq) {
        int row = w0 + lo;
        int byte = (row * 128 + (kq * 16 + hi * 8) * 2) ^ ((row & 7) << 4);
        fa[kq] = *(bf16x8_t*)((char*)vtT + byte);
    }
    float* gp = Gpart + (size_t)blk * 8192;
#pragma unroll
    for (int ct = 0; ct < 2; ++ct) {
        int k0 = (c0 + ct) * 32;
        f32x16_t acc = {};
#pragma unroll
        for (int kq = 0; kq < 4; ++kq) {
            int krow = k0 + lo;
            int byte = (krow * 128 + (kq * 16 + hi * 8) * 2) ^ ((krow & 7) << 4);
            bf16x8_t fb = *(bf16x8_t*)((char*)h2tT + byte);
            acc = __builtin_amdgcn_mfma_f32_32x32x16_bf16(fa[kq], fb, acc, 0, 0, 0);
        }
        // C layout: col=lo -> k, row=(reg&3)+8*(reg>>2)+4*hi -> w (verified mapping)
#pragma unroll
        for (int reg = 0; reg < 16; ++reg) {
            int row = (reg & 3) + 8 * (reg >> 2) + 4 * hi;
            gp[(w0 + row) * 128 + k0 + lo] = acc[reg];
        }
    }

    // svpart: thread t<64 sums row t of vtT (n ascending — same order as before)
    if (t < 64) {
        float s = 0.f;
#pragma unroll
        for (int c = 0; c < 8; ++c) {
            int byte = (t * 128 + c * 16) ^ ((t & 7) << 4);
            uint4 u = *(uint4*)((char*)vtT + byte);
            float d[8];
            bf8_to_f(u, d);
            s += d[0]; s += d[1]; s += d[2]; s += d[3];
            s += d[4]; s += d[5]; s += d[6]; s += d[7];
        }
        svpart[blk * 64 + t] = s;
    }
}

// ---------------- reduce: G = sum Gpart; sv = sum svpart (grid 258) ----------------
__global__ __launch_bounds__(256) void k_gred(const float* __restrict__ Gpart,
                                              const float* __restrict__ svpart,
                                              float* __restrict__ G,
                                              float* __restrict__ sv) {
    __shared__ float red[4][64];
    int blk = blockIdx.x;
    int t = threadIdx.x;
    if (blk < 256) {
        int b  = blk >> 7;
        int es = (blk & 127) << 6;
        int e  = es + (t & 63);
        int cg = t >> 6;
        float s = 0.f;
        const float* gp = Gpart + ((size_t)(b * 256 + cg * 64)) * 8192 + e;
#pragma unroll 8
        for (int c = 0; c < 64; ++c) s += gp[(size_t)c * 8192];
        red[cg][t & 63] = s;
        __syncthreads();
        if (t < 64)
            G[b * 8192 + es + t] = red[0][t] + red[1][t] + red[2][t] + red[3][t];
    } else {
        int b = blk - 256;
        int w = t & 63, cg = t >> 6;
        float s = 0.f;
        const float* sp = svpart + ((size_t)(b * 256 + cg * 64)) * 64 + w;
#pragma unroll 8
        for (int c = 0; c < 64; ++c) s += sp[c * 64];
        red[cg][w] = s;
        __syncthreads();
        if (t < 64) sv[b * 64 + t] = red[0][t] + red[1][t] + red[2][t] + red[3][t];
    }
}

// ---------------- yc: ybar -> C[b][w][k], D[b][w] (grid 32) ----------------
__global__ __launch_bounds__(256) void k_yc(const float* __restrict__ G,
                                            const float* __restrict__ sv,
                                            const float* __restrict__ W3psi,
                                            const float* __restrict__ b3psi,
                                            const float* __restrict__ W3phi,
                                            const float* __restrict__ b3phi,
                                            float* __restrict__ C,
                                            float* __restrict__ D) {
    __shared__ float ybar[256];
    int bq = blockIdx.x;             // 32
    int b = bq >> 4, q = bq & 15;
    int t = threadIdx.x;
    {
        int o = t, w = o >> 2;
        const float* gp = &G[(size_t)(b * 64 + w) * 128];
        float s0 = 0.f, s1 = 0.f, s2 = 0.f, s3 = 0.f;
#pragma unroll 4
        for (int k = 0; k < 128; k += 4) {
            s0 = fmaf(W3psi[(k + 0) * 256 + o], gp[k + 0], s0);
            s1 = fmaf(W3psi[(k + 1) * 256 + o], gp[k + 1], s1);
            s2 = fmaf(W3psi[(k + 2) * 256 + o], gp[k + 2], s2);
            s3 = fmaf(W3psi[(k + 3) * 256 + o], gp[k + 3], s3);
        }
        float s = b3psi[o] * sv[b * 64 + w] + ((s0 + s1) + (s2 + s3));
        ybar[o] = s * (1.f / 16384.f);
    }
    __syncthreads();
#pragma unroll
    for (int rep = 0; rep < 2; ++rep) {
        int e = q * 512 + rep * 256 + t;   // slice of 8192
        int w = e >> 7, k = e & 127;
        const float* wp = &W3phi[k * 256 + w * 4];
        C[b * 8192 + e] = fmaf(wp[0], ybar[w * 4],
                          fmaf(wp[1], ybar[w * 4 + 1],
                          fmaf(wp[2], ybar[w * 4 + 2], wp[3] * ybar[w * 4 + 3])));
    }
    if (q == 0 && t < 64) {
        int w = t;
        D[b * 64 + w] = b3phi[w * 4] * ybar[w * 4] + b3phi[w * 4 + 1] * ybar[w * 4 + 1]
                      + b3phi[w * 4 + 2] * ybar[w * 4 + 2] + b3phi[w * 4 + 3] * ybar[w * 4 + 3];
    }
}

// ---------------- x2c: x2c[px][w] = H2phi[px][:].C[b][w][:] + D[b][w] (grid 1024) ----------------
__global__ __launch_bounds__(256) void k_x2c(const unsigned short* __restrict__ H2phi,
                                             const float* __restrict__ C,
                                             const float* __restrict__ D,
                                             unsigned short* __restrict__ x2c) {
    __shared__ float cl[8192];       // C[b]: [64 w][128 k] (32 KB)
    __shared__ float h2l[4096];      // [32 px][128 k], XOR-swizzled (16 KB)
    __shared__ float Dl[64];
    int blk = blockIdx.x;            // 1024: 512 per b
    int b = blk >> 9;
    int px0 = (blk & 511) << 5;      // 32 px per block
    int t = threadIdx.x;

    const float* cp = C + b * 8192;
#pragma unroll
    for (int r = 0; r < 8; ++r) {
        int f = r * 1024 + t * 4;
        *(float4*)&cl[f] = *(const float4*)&cp[f];
    }
    if (t < 64) Dl[t] = D[b * 64 + t];
    {   // stage H2phi tile (bf16 -> f32), swizzled
        const unsigned short* hsrc = H2phi + ((size_t)(b * 16384 + px0)) * 128;
#pragma unroll
        for (int r = 0; r < 2; ++r) {
            int f = r * 2048 + t * 8;              // float index, 8 per rep
            uint4 u = *(const uint4*)(hsrc + f);
            float d[8];
            bf8_to_f(u, d);
            int px = f >> 7;
            int sw2 = ((px & 7) << 4) ^ (((px >> 3) & 1) << 6);
            *(float4*)((char*)h2l + ((f * 4) ^ sw2))      = make_float4(d[0], d[1], d[2], d[3]);
            *(float4*)((char*)h2l + ((f * 4 + 16) ^ sw2)) = make_float4(d[4], d[5], d[6], d[7]);
        }
    }
    __syncthreads();

    int px = t & 31;
    int w0 = (t >> 5) << 3;          // 0..56: 8 w per thread
    int psw = ((px & 7) << 4) ^ (((px >> 3) & 1) << 6);
    float acc[8];
#pragma unroll
    for (int j = 0; j < 8; ++j) acc[j] = 0.f;

#pragma unroll 4
    for (int kq = 0; kq < 32; ++kq) {
        float4 hq = *(float4*)((char*)h2l + ((px * 512 + kq * 16) ^ psw));
#pragma unroll
        for (int j = 0; j < 8; ++j) {
            float4 cq = *(float4*)&cl[(w0 + j) * 128 + kq * 4];
            acc[j] = fmaf(hq.x, cq.x, acc[j]);
            acc[j] = fmaf(hq.y, cq.y, acc[j]);
            acc[j] = fmaf(hq.z, cq.z, acc[j]);
            acc[j] = fmaf(hq.w, cq.w, acc[j]);
        }
    }
    unsigned short us[8];
#pragma unroll
    for (int j = 0; j < 8; ++j) us[j] = f2bf(acc[j] + Dl[w0 + j]);
    unsigned short* op = x2c + ((size_t)(b * 16384 + px0 + px)) * 64 + w0;
    *(uint4*)op = *(uint4*)us;
}

// ---------------- epilogue: h = LN(x1 + up(yl1) + up(yl2) + up(x2c)); bf16 in/out ----------------
__global__ __launch_bounds__(256) void k_epilogue(const unsigned short* __restrict__ x1,
                                                  const unsigned short* __restrict__ yl1,
                                                  const unsigned short* __restrict__ yl2,
                                                  const unsigned short* __restrict__ x2c,
                                                  const float* __restrict__ lnG,
                                                  const float* __restrict__ lnB,
                                                  unsigned short* __restrict__ hbf,
                                                  int do_relu) {
    __shared__ float y1s[2][10][64];   // yl1 corners (scale 2)
    __shared__ float xcs[2][10][64];   // x2c corners (scale 2)
    __shared__ float y2s[2][6][64];    // yl2 corners (scale 4)
    int t    = threadIdx.x;
    int blk  = blockIdx.x;                 // 8192 = 2 * 256 * 16
    int b    = blk >> 12;
    int rest = blk & 4095;
    int y    = rest >> 4;
    int x0   = (rest & 15) << 4;
    int wv = t >> 6, lane = t & 63;

    Lerp ly1 = lcoord(y, 0.5f, -0.25f, 128);    // yl1 & x2c
    Lerp ly2 = lcoord(y, 0.25f, -0.375f, 64);   // yl2
    int c1 = max(0, (int)floorf((float)x0 * 0.5f - 0.25f));
    int c2 = max(0, (int)floorf((float)x0 * 0.25f - 0.375f));

    const unsigned short* Y1 = yl1 + (size_t)b * 16384 * 64;
    const unsigned short* Y2 = yl2 + (size_t)b * 4096 * 64;
    const unsigned short* XC = x2c + (size_t)b * 16384 * 64;
    for (int f4 = t; f4 < 832; f4 += 256) {
        int e, row, col;
        const unsigned short* src;
        float* dst;
        if (f4 < 320) {                 // y1s
            e = f4 * 4;
            int r = e / 640, rm = e - r * 640;
            int j = rm >> 6, ch = rm & 63;
            row = r ? ly1.i1 : ly1.i0;
            col = min(c1 + j, 127);
            src = &Y1[((size_t)(row * 128 + col)) * 64 + ch];
            dst = &y1s[r][j][ch];
        } else if (f4 < 640) {          // xcs
            e = (f4 - 320) * 4;
            int r = e / 640, rm = e - r * 640;
            int j = rm >> 6, ch = rm & 63;
            row = r ? ly1.i1 : ly1.i0;
            col = min(c1 + j, 127);
            src = &XC[((size_t)(row * 128 + col)) * 64 + ch];
            dst = &xcs[r][j][ch];
        } else {                        // y2s
            e = (f4 - 640) * 4;
            int r = e / 384, rm = e - r * 384;
            int j = rm >> 6, ch = rm & 63;
            row = r ? ly2.i1 : ly2.i0;
            col = min(c2 + j, 63);
            src = &Y2[((size_t)(row * 64 + col)) * 64 + ch];
            dst = &y2s[r][j][ch];
        }
        uint2 u = *(const uint2*)src;   // 4 bf16
        dst[0] = __uint_as_float((u.x & 0xFFFFu) << 16);
        dst[1] = __uint_as_float(u.x & 0xFFFF0000u);
        dst[2] = __uint_as_float((u.y & 0xFFFFu) << 16);
        dst[3] = __uint_as_float(u.y & 0xFFFF0000u);
    }
    __syncthreads();

    float g = lnG[lane], be = lnB[lane];
    for (int pp = 0; pp < 4; ++pp) {
        int xx = x0 + wv * 4 + pp;
        size_t pix = (size_t)((b * 256 + y) * 256 + xx);
        float v = bf2f(x1[pix * 64 + lane]);
        {   // yl1 + x2c (shared x-lerp)
            Lerp lx = lcoord(xx, 0.5f, -0.25f, 128);
            int j0 = lx.i0 - c1, j1 = lx.i1 - c1;
            float a0 = y1s[0][j0][lane], a1 = y1s[0][j1][lane];
            float b0 = y1s[1][j0][lane], b1 = y1s[1][j1][lane];
            float ta = a0 + lx.f * (a1 - a0);
            float tb = b0 + lx.f * (b1 - b0);
            v += ta + ly1.f * (tb - ta);
            float p0 = xcs[0][j0][lane], p1 = xcs[0][j1][lane];
            float q0 = xcs[1][j0][lane], q1 = xcs[1][j1][lane];
            float tp = p0 + lx.f * (p1 - p0);
            float tq = q0 + lx.f * (q1 - q0);
            v += tp + ly1.f * (tq - tp);
        }
        {   // yl2
            Lerp lx = lcoord(xx, 0.25f, -0.375f, 64);
            int j0 = lx.i0 - c2, j1 = lx.i1 - c2;
            float a0 = y2s[0][j0][lane], a1 = y2s[0][j1][lane];
            float b0 = y2s[1][j0][lane], b1 = y2s[1][j1][lane];
            float ta = a0 + lx.f * (a1 - a0);
            float tb = b0 + lx.f * (b1 - b0);
            v += ta + ly2.f * (tb - ta);
        }
        float mu  = wave_sum64(v) * (1.f / 64.f);
        float d   = v - mu;
        float var = wave_sum64(d * d) * (1.f / 64.f);
        float ov  = fmaf(d * rsqrtf(var + 1e-5f), g, be);
        if (do_relu) ov = fmaxf(ov, 0.f);
        hbf[pix * 64 + lane] = f2bf(ov);
    }
}

// ---------------- head (MFMA): out = relu(hbf@q1W+q1b) . q2 + q2b ----------------
__global__ __launch_bounds__(256) void k_head_mfma(
    const unsigned short* __restrict__ hbf,   // [131072][64] bf16
    const unsigned short* __restrict__ q1bf,  // [128 j][64 k] bf16
    const float* __restrict__ q1b,            // [128]
    const float* __restrict__ q2,             // [128]
    const float* __restrict__ q2b,            // [1]
    float* __restrict__ out) {
    __shared__ unsigned short Q[8192];        // [j][k] swizzled
    int t = threadIdx.x;
    for (int c = t; c < 1024; c += 256) {
        int j = c >> 3, slot = c & 7;
        uint4 v = *(const uint4*)(q1bf + j * 64 + slot * 8);
        int byte = (j * 128 + slot * 16) ^ ((j & 7) << 4);
        *(uint4*)((char*)Q + byte) = v;
    }
    __syncthreads();

    int w = t >> 6, lane = t & 63;
    int lo = lane & 31, hi = lane >> 5;
    int px0 = blockIdx.x * 128 + w * 32;      // grid 1024

    bf16x8_t av[4];
    const unsigned short* hp = hbf + (size_t)(px0 + lo) * 64 + hi * 8;
#pragma unroll
    for (int ks = 0; ks < 4; ++ks)
        av[ks] = *(const bf16x8_t*)(hp + ks * 16);

    float res[16];
#pragma unroll
    for (int r = 0; r < 16; ++r) res[r] = 0.f;

#pragma unroll
    for (int jb = 0; jb < 4; ++jb) {
        f32x16_t acc = {};
        int j = jb * 32 + lo;
#pragma unroll
        for (int ks = 0; ks < 4; ++ks) {
            int byte = (j * 128 + ks * 32 + hi * 16) ^ ((j & 7) << 4);
            bf16x8_t bv = *(bf16x8_t*)((char*)Q + byte);
            acc = __builtin_amdgcn_mfma_f32_32x32x16_bf16(av[ks], bv, acc, 0, 0, 0);
        }
        float b1 = q1b[j];
        float w2 = q2[j];
#pragma unroll
        for (int r = 0; r < 16; ++r)
            res[r] = fmaf(fmaxf(acc[r] + b1, 0.f), w2, res[r]);
    }
#pragma unroll
    for (int r = 0; r < 16; ++r) {
        float v = res[r];
        v += __shfl_xor(v, 1);
        v += __shfl_xor(v, 2);
        v += __shfl_xor(v, 4);
        v += __shfl_xor(v, 8);
        v += __shfl_xor(v, 16);
        res[r] = v;
    }
    if (lo == 0) {
        float qb = q2b[0];
#pragma unroll
        for (int r = 0; r < 16; ++r) {
            int row = (r & 3) + 8 * (r >> 2) + 4 * hi;
            out[px0 + row] = res[r] + qb;
        }
    }
}

// ---------------- launch ----------------
extern "C" void kernel_launch(void* const* d_in, const int* in_sizes, int n_in,
                              void* d_out, int out_size, void* d_ws, size_t ws_size,
                              hipStream_t stream) {
    const float* x     = (const float*)d_in[0];
    const float* a     = (const float*)d_in[1];
    const float* pW    = (const float*)d_in[2];
    const float* pb    = (const float*)d_in[3];
    const float* q1W   = (const float*)d_in[4];
    const float* q1b   = (const float*)d_in[5];
    const float* q2W   = (const float*)d_in[6];
    const float* q2b   = (const float*)d_in[7];
    const float* phiW1 = (const float*)d_in[8];
    const float* phib1 = (const float*)d_in[9];
    const float* phiW2 = (const float*)d_in[10];
    const float* phib2 = (const float*)d_in[11];
    const float* phiW3 = (const float*)d_in[12];
    const float* phib3 = (const float*)d_in[13];
    const float* psiW1 = (const float*)d_in[14];
    const float* psib1 = (const float*)d_in[15];
    const float* psiW2 = (const float*)d_in[16];
    const float* psib2 = (const float*)d_in[17];
    const float* psiW3 = (const float*)d_in[18];
    const float* psib3 = (const float*)d_in[19];
    const float* lnG   = (const float*)d_in[20];
    const float* lnB   = (const float*)d_in[21];
    const float* convW = (const float*)d_in[22];
    const float* convb = (const float*)d_in[23];

    float* ws = (float*)d_ws;
    unsigned short* x1    = (unsigned short*)(ws + OFF_X1);
    unsigned short* yl1   = (unsigned short*)(ws + OFF_YL1);
    unsigned short* yl2   = (unsigned short*)(ws + OFF_YL2);
    unsigned short* hbf   = (unsigned short*)(ws + OFF_HBF);
    unsigned short* H2psi = (unsigned short*)(ws + OFF_H2PSI);
    unsigned short* x2c   = (unsigned short*)(ws + OFF_H2PSI);  // overlay: H2psi dead after k_gpart
    unsigned short* H2phi = (unsigned short*)(ws + OFF_H2PHI);
    unsigned short* cwtbf = (unsigned short*)(ws + OFF_CWTBF);
    unsigned short* q1bf  = (unsigned short*)(ws + OFF_Q1BF);
    unsigned short* w2t   = (unsigned short*)(ws + OFF_W2T);
    float* Gpart = ws + OFF_GPART;
    float* svpart= ws + OFF_SVP;
    float* G     = ws + OFF_G;
    float* sv    = ws + OFF_SV;
    float* C     = ws + OFF_C;
    float* D     = ws + OFF_D;

    k_setup<<<2528, 256, 0, stream>>>(convW, cwtbf, q1W, q1bf,
                                      psiW2, phiW2, w2t, x, a, pW, pb, hbf);

    for (int i = 0; i < 4; ++i) {
        k_convmlp<<<2368, 256, 0, stream>>>(hbf, cwtbf, convb, x1, yl1, yl2,
                                            a, x,
                                            psiW1 + i * 192, psib1 + i * 64, psib2 + i * 128,
                                            phiW1 + i * 192, phib1 + i * 64, phib2 + i * 128,
                                            w2t, H2psi, H2phi, i);
        k_gpart<<<512, 256, 0, stream>>>(hbf, H2psi, Gpart, svpart);
        k_gred<<<258, 256, 0, stream>>>(Gpart, svpart, G, sv);
        k_yc<<<32, 256, 0, stream>>>(G, sv,
                                     psiW3 + (size_t)i * 32768, psib3 + i * 256,
                                     phiW3 + (size_t)i * 32768, phib3 + i * 256,
                                     C, D);
        k_x2c<<<1024, 256, 0, stream>>>(H2phi, C, D, x2c);
        k_epilogue<<<8192, 256, 0, stream>>>(x1, yl1, yl2, x2c,
                                             lnG + i * 64, lnB + i * 64,
                                             hbf, (i < 3) ? 1 : 0);
    }

    k_head_mfma<<<1024, 256, 0, stream>>>(hbf, q1bf, q1b, q2W, q2b, (float*)d_out);
}